// Round 4
// baseline (1810.849 us; speedup 1.0000x reference)
//
#include <hip/hip_runtime.h>

#define NN 50000
#define NE 800000
#define NG 512
#define HC 64
#define NL 5
#define GD_COLS 321
#define BN_EPS 1e-5f
#define NT 196  // scan tiles of 256 covering NN

// ---------------- CSR build (edges sorted by dst), done once per call ----------------

__global__ void hist_kernel(const int* __restrict__ ei, int* __restrict__ counts) {
    int e = blockIdx.x * blockDim.x + threadIdx.x;
    if (e < NE) atomicAdd(&counts[ei[NE + e]], 1);
}

__global__ void scan_a_kernel(const int* __restrict__ counts, int* __restrict__ row_start,
                              int* __restrict__ tile_sums) {
    __shared__ int sh[256];
    int t = threadIdx.x;
    int i = blockIdx.x * 256 + t;
    int c = (i < NN) ? counts[i] : 0;
    sh[t] = c;
    __syncthreads();
    for (int ofs = 1; ofs < 256; ofs <<= 1) {
        int v = (t >= ofs) ? sh[t - ofs] : 0;
        __syncthreads();
        sh[t] += v;
        __syncthreads();
    }
    if (i < NN) row_start[i] = sh[t] - c;
    if (t == 255) tile_sums[blockIdx.x] = sh[255];
}

__global__ void scan_b_kernel(int* __restrict__ tile_sums) {
    __shared__ int sh[256];
    int t = threadIdx.x;
    int v = (t < NT) ? tile_sums[t] : 0;
    sh[t] = v;
    __syncthreads();
    for (int ofs = 1; ofs < 256; ofs <<= 1) {
        int u = (t >= ofs) ? sh[t - ofs] : 0;
        __syncthreads();
        sh[t] += u;
        __syncthreads();
    }
    if (t < NT) tile_sums[t] = sh[t] - v;
}

__global__ void scan_c_kernel(int* __restrict__ row_start, const int* __restrict__ tile_sums,
                              int* __restrict__ cursor) {
    int i = blockIdx.x * 256 + threadIdx.x;
    if (i < NN) {
        int v = row_start[i] + tile_sums[blockIdx.x];
        row_start[i] = v;
        cursor[i] = v;
    }
    if (i == 0) row_start[NN] = NE;
}

__global__ void scatter_kernel(const int* __restrict__ ei, int* __restrict__ cursor,
                               int2* __restrict__ sedge) {
    int e = blockIdx.x * blockDim.x + threadIdx.x;
    if (e < NE) {
        int s = ei[e];
        int d = ei[NE + e];
        int pos = atomicAdd(&cursor[d], 1);
        sedge[pos] = make_int2(s, d);
    }
}

// ---------------- layer 0 (C_IN = 1) ----------------

__global__ void gather0_kernel(const float* __restrict__ x, const int* __restrict__ row_start,
                               const int2* __restrict__ sedge, float* __restrict__ z0) {
    int i = blockIdx.x * blockDim.x + threadIdx.x;
    if (i < NN) {
        float acc = x[i];
        int p = row_start[i];
        int pb = row_start[i + 1];
        for (; p + 4 <= pb; p += 4) {
            float v0 = x[sedge[p].x], v1 = x[sedge[p + 1].x];
            float v2 = x[sedge[p + 2].x], v3 = x[sedge[p + 3].x];
            acc += (v0 + v1) + (v2 + v3);
        }
        for (; p < pb; ++p) acc += x[sedge[p].x];
        z0[i] = acc;
    }
}

__global__ void rank1_stats_kernel(const float* __restrict__ z0, const float* __restrict__ w,
                                   const float* __restrict__ bias, float* __restrict__ y,
                                   float* __restrict__ stats) {
    int lane = threadIdx.x & 63;
    int wid = threadIdx.x >> 6;
    int r0 = blockIdx.x * 64 + wid * 16;
    float wv = w[lane];
    float bv = bias[lane];
    float s = 0.f, s2 = 0.f;
    for (int j = 0; j < 16; ++j) {
        int r = r0 + j;
        if (r < NN) {
            float v = z0[r] * wv + bv;
            y[r * HC + lane] = v;
            s += v;
            s2 += v * v;
        }
    }
    __shared__ float ls[256], ls2[256];
    ls[threadIdx.x] = s;
    ls2[threadIdx.x] = s2;
    __syncthreads();
    if (wid == 0) {
        float ts = ls[lane] + ls[64 + lane] + ls[128 + lane] + ls[192 + lane];
        float t2 = ls2[lane] + ls2[64 + lane] + ls2[128 + lane] + ls2[192 + lane];
        atomicAdd(&stats[lane], ts);
        atomicAdd(&stats[64 + lane], t2);
    }
}

// ---------------- K1: BN2(prev)+ReLU fused gather (edge-parallel, LDS atomics)
//                  + gdesc(prev layer) + GEMM1 + stats1 ----------------
__global__ __launch_bounds__(256) void gather_gemm_kernel(
    const float* __restrict__ u, const float* __restrict__ statsPrev,
    const float* __restrict__ gPrev, const float* __restrict__ bPrev,
    const int* __restrict__ row_start, const int2* __restrict__ sedge,
    const float* __restrict__ w, const float* __restrict__ bias, const int* __restrict__ batch,
    float* __restrict__ gdesc, int layerPrev, float* __restrict__ out,
    float* __restrict__ statsOut) {
    __shared__ float zs[32 * 64];
    __shared__ float wsm[64 * 64];
    __shared__ float a1[64], s1[64];
    __shared__ float red[256];
    int t = threadIdx.x, lane = t & 63, wid = t >> 6;
    int r0 = blockIdx.x * 32;
    if (t < 64) {
        float mu = statsPrev[t] * (1.0f / NN);
        float var = statsPrev[64 + t] * (1.0f / NN) - mu * mu;
        float a = gPrev[t] * rsqrtf(var + BN_EPS);
        a1[t] = a;
        s1[t] = bPrev[t] - mu * a;
    }
    for (int idx = t; idx < 1024; idx += 256)
        *(float4*)&wsm[idx * 4] = *(const float4*)&w[idx * 4];
    __syncthreads();
    float av = a1[lane], sv = s1[lane];
    // self-term init (h = relu(bn(u))) + segmented gdesc accumulation for layerPrev
    {
        int col = 1 + layerPrev * HC + lane;
        float acc = 0.f;
        int cur = -1;
        for (int j = 0; j < 8; ++j) {
            int lr = wid * 8 + j, gr = r0 + lr;
            float v = 0.f;
            if (gr < NN) {
                v = fmaxf(u[gr * HC + lane] * av + sv, 0.f);
                int gid = batch[gr];
                if (gid != cur) {
                    if (cur >= 0) atomicAdd(&gdesc[cur * GD_COLS + col], acc);
                    cur = gid;
                    acc = 0.f;
                }
                acc += v;
            }
            zs[lr * 64 + lane] = v;
        }
        if (cur >= 0) atomicAdd(&gdesc[cur * GD_COLS + col], acc);
    }
    __syncthreads();
    // edge-parallel gather: all 4 waves share the tile's contiguous edge range
    int rend = r0 + 32;
    if (rend > NN) rend = NN;
    if (r0 < NN) {
        int pa = row_start[r0];
        int pb = row_start[rend];
        for (int p0 = pa + wid * 8; p0 < pb; p0 += 32) {
            int cnt = pb - p0;
            if (cnt >= 8) {
                int2 e[8];
#pragma unroll
                for (int q = 0; q < 8; ++q) e[q] = sedge[p0 + q];
                float v[8];
#pragma unroll
                for (int q = 0; q < 8; ++q) v[q] = u[e[q].x * HC + lane];
#pragma unroll
                for (int q = 0; q < 8; ++q)
                    atomicAdd(&zs[(e[q].y - r0) * 64 + lane], fmaxf(v[q] * av + sv, 0.f));
            } else {
                for (int q = 0; q < cnt; ++q) {
                    int2 e = sedge[p0 + q];
                    float v = fmaxf(u[e.x * HC + lane] * av + sv, 0.f);
                    atomicAdd(&zs[(e.y - r0) * 64 + lane], v);
                }
            }
        }
    }
    __syncthreads();
    // GEMM1 + stats1
    float bv = bias[lane];
    float ssum = 0.f, ssq = 0.f;
    for (int j = 0; j < 8; ++j) {
        int r = wid * 8 + j;
        float acc = 0.f;
#pragma unroll
        for (int k = 0; k < 64; k += 4) {
            float4 zv = *(const float4*)&zs[r * 64 + k];
            acc += zv.x * wsm[(k + 0) * 64 + lane];
            acc += zv.y * wsm[(k + 1) * 64 + lane];
            acc += zv.z * wsm[(k + 2) * 64 + lane];
            acc += zv.w * wsm[(k + 3) * 64 + lane];
        }
        acc += bv;
        int gr = r0 + r;
        if (gr < NN) {
            out[gr * HC + lane] = acc;
            ssum += acc;
            ssq += acc * acc;
        }
    }
    red[t] = ssum;
    __syncthreads();
    if (wid == 0) {
        float ts = red[lane] + red[64 + lane] + red[128 + lane] + red[192 + lane];
        atomicAdd(&statsOut[lane], ts);
    }
    __syncthreads();
    red[t] = ssq;
    __syncthreads();
    if (wid == 0) {
        float t2 = red[lane] + red[64 + lane] + red[128 + lane] + red[192 + lane];
        atomicAdd(&statsOut[64 + lane], t2);
    }
}

// ---------------- K2: BN1+ReLU fused GEMM2 + stats2 (32 rows/block) ----------------
__global__ __launch_bounds__(256) void gemm64_norm_kernel(
    const float* __restrict__ in, const float* __restrict__ w, const float* __restrict__ bias,
    const float* __restrict__ statsIn, const float* __restrict__ gIn,
    const float* __restrict__ bIn, float* __restrict__ out, float* __restrict__ statsOut) {
    __shared__ float zs[32 * 64];
    __shared__ float wsm[64 * 64];
    __shared__ float a1[64], s1[64];
    __shared__ float red[256];
    int t = threadIdx.x;
    if (t < 64) {
        float mu = statsIn[t] * (1.0f / NN);
        float var = statsIn[64 + t] * (1.0f / NN) - mu * mu;
        float a = gIn[t] * rsqrtf(var + BN_EPS);
        a1[t] = a;
        s1[t] = bIn[t] - mu * a;
    }
    __syncthreads();
    int r0 = blockIdx.x * 32;
    for (int idx = t; idx < 512; idx += 256) {
        int off = idx * 4;
        int r = r0 + (off >> 6);
        int k = off & 63;
        float4 v;
        if (r < NN)
            v = *(const float4*)&in[r * HC + k];
        else
            v = make_float4(0.f, 0.f, 0.f, 0.f);
        v.x = fmaxf(v.x * a1[k] + s1[k], 0.f);
        v.y = fmaxf(v.y * a1[k + 1] + s1[k + 1], 0.f);
        v.z = fmaxf(v.z * a1[k + 2] + s1[k + 2], 0.f);
        v.w = fmaxf(v.w * a1[k + 3] + s1[k + 3], 0.f);
        *(float4*)&zs[off] = v;
    }
    for (int idx = t; idx < 1024; idx += 256) {
        int off = idx * 4;
        *(float4*)&wsm[off] = *(const float4*)&w[off];
    }
    __syncthreads();
    int lane = t & 63, wid = t >> 6;
    float bv = bias[lane];
    float ssum = 0.f, ssq = 0.f;
    for (int j = 0; j < 8; ++j) {
        int r = wid * 8 + j;
        float acc = 0.f;
#pragma unroll
        for (int k = 0; k < 64; k += 4) {
            float4 zv = *(const float4*)&zs[r * 64 + k];
            acc += zv.x * wsm[(k + 0) * 64 + lane];
            acc += zv.y * wsm[(k + 1) * 64 + lane];
            acc += zv.z * wsm[(k + 2) * 64 + lane];
            acc += zv.w * wsm[(k + 3) * 64 + lane];
        }
        acc += bv;
        int gr = r0 + r;
        if (gr < NN) {
            out[gr * HC + lane] = acc;
            ssum += acc;
            ssq += acc * acc;
        }
    }
    red[t] = ssum;
    __syncthreads();
    if (wid == 0) {
        float ts = red[lane] + red[64 + lane] + red[128 + lane] + red[192 + lane];
        atomicAdd(&statsOut[lane], ts);
    }
    __syncthreads();
    red[t] = ssq;
    __syncthreads();
    if (wid == 0) {
        float t2 = red[lane] + red[64 + lane] + red[128 + lane] + red[192 + lane];
        atomicAdd(&statsOut[64 + lane], t2);
    }
}

// ---------------- last-layer gdesc (BN2+ReLU, segmented sum, no h write) ----------------
#define CHK 16
__global__ void gdesc_last_kernel(const float* __restrict__ u, const float* __restrict__ stats,
                                  const float* __restrict__ g, const float* __restrict__ b,
                                  const int* __restrict__ batch, float* __restrict__ gdesc,
                                  int layer) {
    int lane = threadIdx.x & 63;
    int wid = threadIdx.x >> 6;
    int i0 = (blockIdx.x * 4 + wid) * CHK;
    if (i0 >= NN) return;
    float mu = stats[lane] * (1.0f / NN);
    float var = stats[64 + lane] * (1.0f / NN) - mu * mu;
    float a = g[lane] * rsqrtf(var + BN_EPS);
    float s = b[lane] - mu * a;
    int col = 1 + layer * HC + lane;
    float acc = 0.f;
    int cur = -1;
    int iend = i0 + CHK;
    if (iend > NN) iend = NN;
    for (int i = i0; i < iend; ++i) {
        int gid = batch[i];
        if (gid != cur) {
            if (cur >= 0) atomicAdd(&gdesc[cur * GD_COLS + col], acc);
            cur = gid;
            acc = 0.f;
        }
        acc += fmaxf(u[i * HC + lane] * a + s, 0.f);
    }
    if (cur >= 0) atomicAdd(&gdesc[cur * GD_COLS + col], acc);
}

__global__ void first_desc_kernel(const float* __restrict__ x, const int* __restrict__ batch,
                                  float* __restrict__ gdesc) {
    int i = blockIdx.x * blockDim.x + threadIdx.x;
    if (i < NN) atomicAdd(&gdesc[batch[i] * GD_COLS], x[i]);
}

__global__ void final_gemm_kernel(const float* __restrict__ gdesc, const float* __restrict__ lw,
                                  const float* __restrict__ lb, float* __restrict__ out) {
    int g = blockIdx.x;
    int lane = threadIdx.x;  // 64
    float a0 = 0.f, a1 = 0.f;
    for (int j = lane; j < GD_COLS; j += 64) {
        float v = gdesc[g * GD_COLS + j];
        a0 += v * lw[j * 2 + 0];
        a1 += v * lw[j * 2 + 1];
    }
    for (int off = 32; off > 0; off >>= 1) {
        a0 += __shfl_down(a0, off);
        a1 += __shfl_down(a1, off);
    }
    if (lane == 0) {
        out[g * 2 + 0] = a0 + lb[0];
        out[g * 2 + 1] = a1 + lb[1];
    }
}

extern "C" void kernel_launch(void* const* d_in, const int* in_sizes, int n_in, void* d_out,
                              int out_size, void* d_ws, size_t ws_size, hipStream_t stream) {
    const float* x = (const float*)d_in[0];
    const int* ei = (const int*)d_in[1];
    const int* batch = (const int*)d_in[2];
    const float* w1_0 = (const float*)d_in[3];
    const float* w1_rest = (const float*)d_in[4];
    const float* b1 = (const float*)d_in[5];
    const float* gm = (const float*)d_in[6];
    const float* bm = (const float*)d_in[7];
    const float* w2 = (const float*)d_in[8];
    const float* b2 = (const float*)d_in[9];
    const float* go = (const float*)d_in[10];
    const float* bo = (const float*)d_in[11];
    const float* lw = (const float*)d_in[12];
    const float* lb = (const float*)d_in[13];
    float* out = (float*)d_out;

    float* ybuf = (float*)d_ws;                  // N*64
    float* ubuf = ybuf + (size_t)NN * HC;        // N*64
    float* z0 = ubuf + (size_t)NN * HC;          // N
    float* stats = z0 + NN;                      // NL*256
    float* gdesc = stats + NL * 256;             // NG*321
    int2* sedge = (int2*)(gdesc + (size_t)NG * GD_COLS + 64);  // NE int2 (8B-aligned)
    int* row_start = (int*)(sedge + NE);         // NN+1
    int* cursor = row_start + NN + 1;            // NN (also counts)
    int* tile_sums = cursor + NN;                // 256

    hipMemsetAsync(stats, 0, (NL * 256 + NG * GD_COLS) * sizeof(float), stream);
    hipMemsetAsync(cursor, 0, NN * sizeof(int), stream);  // counts

    // ---- CSR build (once; edges constant across layers) ----
    hist_kernel<<<(NE + 255) / 256, 256, 0, stream>>>(ei, cursor);
    scan_a_kernel<<<NT, 256, 0, stream>>>(cursor, row_start, tile_sums);
    scan_b_kernel<<<1, 256, 0, stream>>>(tile_sums);
    scan_c_kernel<<<NT, 256, 0, stream>>>(row_start, tile_sums, cursor);
    scatter_kernel<<<(NE + 255) / 256, 256, 0, stream>>>(ei, cursor, sedge);

    // ---- layer 0 ----
    gather0_kernel<<<NT, 256, 0, stream>>>(x, row_start, sedge, z0);
    rank1_stats_kernel<<<(NN + 63) / 64, 256, 0, stream>>>(z0, w1_0, b1, ybuf, stats);
    gemm64_norm_kernel<<<(NN + 31) / 32, 256, 0, stream>>>(ybuf, w2, b2, stats, gm, bm, ubuf,
                                                           stats + 128);

    // ---- layers 1..4 (K1 applies BN2 of prev layer + gdesc of prev layer) ----
    for (int l = 1; l < NL; ++l) {
        float* st1 = stats + l * 256;
        float* st2 = st1 + 128;
        float* stPrev = stats + (l - 1) * 256 + 128;
        gather_gemm_kernel<<<(NN + 31) / 32, 256, 0, stream>>>(
            ubuf, stPrev, go + (l - 1) * HC, bo + (l - 1) * HC, row_start, sedge,
            w1_rest + (size_t)(l - 1) * HC * HC, b1 + l * HC, batch, gdesc, l - 1, ybuf, st1);
        gemm64_norm_kernel<<<(NN + 31) / 32, 256, 0, stream>>>(
            ybuf, w2 + (size_t)l * HC * HC, b2 + l * HC, st1, gm + l * HC, bm + l * HC, ubuf, st2);
    }

    gdesc_last_kernel<<<(NN + 4 * CHK - 1) / (4 * CHK), 256, 0, stream>>>(
        ubuf, stats + 4 * 256 + 128, go + 4 * HC, bo + 4 * HC, batch, gdesc, 4);
    first_desc_kernel<<<(NN + 255) / 256, 256, 0, stream>>>(x, batch, gdesc);
    final_gemm_kernel<<<NG, 64, 0, stream>>>(gdesc, lw, lb, out);
}

// Round 5
// 905.122 us; speedup vs baseline: 2.0007x; 2.0007x over previous
//
#include <hip/hip_runtime.h>

#define NN 50000
#define NE 800000
#define NG 512
#define HC 64
#define NL 5
#define GD_COLS 321
#define BN_EPS 1e-5f
#define NT 196  // scan tiles of 256 covering NN

typedef unsigned short bf16_t;

static __device__ __forceinline__ bf16_t f2bf(float f) {
    unsigned u = __float_as_uint(f);
    unsigned r = (u + 0x7FFFu + ((u >> 16) & 1u)) >> 16;
    return (bf16_t)r;
}
static __device__ __forceinline__ float bf2f(bf16_t h) {
    return __uint_as_float(((unsigned)h) << 16);
}

// ---------------- CSR build (edges sorted by dst), once per call ----------------

__global__ void hist_kernel(const int* __restrict__ ei, int* __restrict__ counts) {
    int e = blockIdx.x * blockDim.x + threadIdx.x;
    if (e < NE) atomicAdd(&counts[ei[NE + e]], 1);
}

__global__ void scan_a_kernel(const int* __restrict__ counts, int* __restrict__ row_start,
                              int* __restrict__ tile_sums) {
    __shared__ int sh[256];
    int t = threadIdx.x;
    int i = blockIdx.x * 256 + t;
    int c = (i < NN) ? counts[i] : 0;
    sh[t] = c;
    __syncthreads();
    for (int ofs = 1; ofs < 256; ofs <<= 1) {
        int v = (t >= ofs) ? sh[t - ofs] : 0;
        __syncthreads();
        sh[t] += v;
        __syncthreads();
    }
    if (i < NN) row_start[i] = sh[t] - c;
    if (t == 255) tile_sums[blockIdx.x] = sh[255];
}

__global__ void scan_b_kernel(int* __restrict__ tile_sums) {
    __shared__ int sh[256];
    int t = threadIdx.x;
    int v = (t < NT) ? tile_sums[t] : 0;
    sh[t] = v;
    __syncthreads();
    for (int ofs = 1; ofs < 256; ofs <<= 1) {
        int u = (t >= ofs) ? sh[t - ofs] : 0;
        __syncthreads();
        sh[t] += u;
        __syncthreads();
    }
    if (t < NT) tile_sums[t] = sh[t] - v;
}

__global__ void scan_c_kernel(int* __restrict__ row_start, const int* __restrict__ tile_sums,
                              int* __restrict__ cursor) {
    int i = blockIdx.x * 256 + threadIdx.x;
    if (i < NN) {
        int v = row_start[i] + tile_sums[blockIdx.x];
        row_start[i] = v;
        cursor[i] = v;
    }
    if (i == 0) row_start[NN] = NE;
}

__global__ void scatter_kernel(const int* __restrict__ ei, int* __restrict__ cursor,
                               int* __restrict__ ssrc) {
    int e = blockIdx.x * blockDim.x + threadIdx.x;
    if (e < NE) {
        int d = ei[NE + e];
        int pos = atomicAdd(&cursor[d], 1);
        ssrc[pos] = ei[e];
    }
}

// ---------------- layer 0: fused gather0 + rank-1 expand + stats ----------------
// block = 256, 64 nodes/block. Phase 1: threads 0..63 compute z0 for the tile.
// Phase 2: 4 waves expand 16 nodes each: y[r][lane] = z0[r]*w[lane]+b[lane] (bf16 out).
__global__ __launch_bounds__(256) void layer0_kernel(const float* __restrict__ x,
                                                     const int* __restrict__ row_start,
                                                     const int* __restrict__ ssrc,
                                                     const float* __restrict__ w,
                                                     const float* __restrict__ bias,
                                                     bf16_t* __restrict__ y,
                                                     float* __restrict__ stats) {
    __shared__ float z0s[64];
    int t = threadIdx.x, lane = t & 63, wid = t >> 6;
    int r0 = blockIdx.x * 64;
    if (t < 64) {
        int i = r0 + t;
        float acc = 0.f;
        if (i < NN) {
            acc = x[i];
            int p = row_start[i], pb = row_start[i + 1];
            for (; p + 4 <= pb; p += 4) {
                float v0 = x[ssrc[p]], v1 = x[ssrc[p + 1]];
                float v2 = x[ssrc[p + 2]], v3 = x[ssrc[p + 3]];
                acc += (v0 + v1) + (v2 + v3);
            }
            for (; p < pb; ++p) acc += x[ssrc[p]];
        }
        z0s[t] = acc;
    }
    __syncthreads();
    float wv = w[lane], bv = bias[lane];
    float s = 0.f, s2 = 0.f;
    for (int j = 0; j < 16; ++j) {
        int r = r0 + wid * 16 + j;
        if (r < NN) {
            float v = z0s[wid * 16 + j] * wv + bv;
            y[r * HC + lane] = f2bf(v);
            s += v;
            s2 += v * v;
        }
    }
    __shared__ float ls[256], ls2[256];
    ls[t] = s;
    ls2[t] = s2;
    __syncthreads();
    if (wid == 0) {
        float ts = ls[lane] + ls[64 + lane] + ls[128 + lane] + ls[192 + lane];
        float t2 = ls2[lane] + ls2[64 + lane] + ls2[128 + lane] + ls2[192 + lane];
        atomicAdd(&stats[lane], ts);
        atomicAdd(&stats[64 + lane], t2);
    }
}

// ---------------- K1: BN2(prev)+ReLU fused gather (register chains)
//                  + gdesc(prev layer) + GEMM1 + stats1 ----------------
__global__ __launch_bounds__(256) void gather_gemm_kernel(
    const bf16_t* __restrict__ u, const float* __restrict__ statsPrev,
    const float* __restrict__ gPrev, const float* __restrict__ bPrev,
    const int* __restrict__ row_start, const int* __restrict__ ssrc,
    const float* __restrict__ w, const float* __restrict__ bias, const int* __restrict__ batch,
    float* __restrict__ gdesc, int layerPrev, bf16_t* __restrict__ out,
    float* __restrict__ statsOut) {
    __shared__ float zs[32 * 64];
    __shared__ float wsm[64 * 64];
    __shared__ float a1[64], s1[64];
    __shared__ float red[256];
    int t = threadIdx.x, lane = t & 63, wid = t >> 6;
    int r0 = blockIdx.x * 32;
    if (t < 64) {
        float mu = statsPrev[t] * (1.0f / NN);
        float var = statsPrev[64 + t] * (1.0f / NN) - mu * mu;
        float a = gPrev[t] * rsqrtf(var + BN_EPS);
        a1[t] = a;
        s1[t] = bPrev[t] - mu * a;
    }
    for (int idx = t; idx < 1024; idx += 256)
        *(float4*)&wsm[idx * 4] = *(const float4*)&w[idx * 4];
    __syncthreads();
    float av = a1[lane], sv = s1[lane];
    // per-node register-chain gather (BN2+ReLU applied to every row on the fly)
    // + segmented gdesc accumulation of the self terms (h of prev layer)
    {
        int col = 1 + layerPrev * HC + lane;
        float gacc = 0.f;
        int cur = -1;
        for (int j = 0; j < 8; ++j) {
            int lr = wid * 8 + j, gr = r0 + lr;
            float acc = 0.f;
            if (gr < NN) {
                float hv = fmaxf(bf2f(u[gr * HC + lane]) * av + sv, 0.f);
                int gid = batch[gr];
                if (gid != cur) {
                    if (cur >= 0) atomicAdd(&gdesc[cur * GD_COLS + col], gacc);
                    cur = gid;
                    gacc = 0.f;
                }
                gacc += hv;
                acc = hv;
                int p = row_start[gr], pb = row_start[gr + 1];
                for (; p + 8 <= pb; p += 8) {
                    int s0 = ssrc[p + 0], s1i = ssrc[p + 1], s2 = ssrc[p + 2], s3 = ssrc[p + 3];
                    int s4 = ssrc[p + 4], s5 = ssrc[p + 5], s6 = ssrc[p + 6], s7 = ssrc[p + 7];
                    float v0 = bf2f(u[s0 * HC + lane]), v1 = bf2f(u[s1i * HC + lane]);
                    float v2 = bf2f(u[s2 * HC + lane]), v3 = bf2f(u[s3 * HC + lane]);
                    float v4 = bf2f(u[s4 * HC + lane]), v5 = bf2f(u[s5 * HC + lane]);
                    float v6 = bf2f(u[s6 * HC + lane]), v7 = bf2f(u[s7 * HC + lane]);
                    v0 = fmaxf(v0 * av + sv, 0.f);
                    v1 = fmaxf(v1 * av + sv, 0.f);
                    v2 = fmaxf(v2 * av + sv, 0.f);
                    v3 = fmaxf(v3 * av + sv, 0.f);
                    v4 = fmaxf(v4 * av + sv, 0.f);
                    v5 = fmaxf(v5 * av + sv, 0.f);
                    v6 = fmaxf(v6 * av + sv, 0.f);
                    v7 = fmaxf(v7 * av + sv, 0.f);
                    acc += ((v0 + v1) + (v2 + v3)) + ((v4 + v5) + (v6 + v7));
                }
                for (; p < pb; ++p)
                    acc += fmaxf(bf2f(u[ssrc[p] * HC + lane]) * av + sv, 0.f);
            }
            zs[lr * 64 + lane] = acc;
        }
        if (cur >= 0) atomicAdd(&gdesc[cur * GD_COLS + col], gacc);
    }
    __syncthreads();
    // GEMM1 + stats1
    float bv = bias[lane];
    float ssum = 0.f, ssq = 0.f;
    for (int j = 0; j < 8; ++j) {
        int r = wid * 8 + j;
        float acc = 0.f;
#pragma unroll
        for (int k = 0; k < 64; k += 4) {
            float4 zv = *(const float4*)&zs[r * 64 + k];
            acc += zv.x * wsm[(k + 0) * 64 + lane];
            acc += zv.y * wsm[(k + 1) * 64 + lane];
            acc += zv.z * wsm[(k + 2) * 64 + lane];
            acc += zv.w * wsm[(k + 3) * 64 + lane];
        }
        acc += bv;
        int gr = r0 + r;
        if (gr < NN) {
            out[gr * HC + lane] = f2bf(acc);
            ssum += acc;
            ssq += acc * acc;
        }
    }
    red[t] = ssum;
    __syncthreads();
    if (wid == 0) {
        float ts = red[lane] + red[64 + lane] + red[128 + lane] + red[192 + lane];
        atomicAdd(&statsOut[lane], ts);
    }
    __syncthreads();
    red[t] = ssq;
    __syncthreads();
    if (wid == 0) {
        float t2 = red[lane] + red[64 + lane] + red[128 + lane] + red[192 + lane];
        atomicAdd(&statsOut[64 + lane], t2);
    }
}

// ---------------- K2: BN1+ReLU fused GEMM2 + stats2 (32 rows/block, bf16 io) ----------------
__global__ __launch_bounds__(256) void gemm64_norm_kernel(
    const bf16_t* __restrict__ in, const float* __restrict__ w, const float* __restrict__ bias,
    const float* __restrict__ statsIn, const float* __restrict__ gIn,
    const float* __restrict__ bIn, bf16_t* __restrict__ out, float* __restrict__ statsOut) {
    __shared__ float zs[32 * 64];
    __shared__ float wsm[64 * 64];
    __shared__ float a1[64], s1[64];
    __shared__ float red[256];
    int t = threadIdx.x;
    if (t < 64) {
        float mu = statsIn[t] * (1.0f / NN);
        float var = statsIn[64 + t] * (1.0f / NN) - mu * mu;
        float a = gIn[t] * rsqrtf(var + BN_EPS);
        a1[t] = a;
        s1[t] = bIn[t] - mu * a;
    }
    __syncthreads();
    int r0 = blockIdx.x * 32;
    for (int idx = t; idx < 512; idx += 256) {
        int off = idx * 4;
        int r = r0 + (off >> 6);
        int k = off & 63;
        float4 v = make_float4(0.f, 0.f, 0.f, 0.f);
        if (r < NN) {
            ushort4 uv = *(const ushort4*)&in[r * HC + k];
            v.x = bf2f(uv.x);
            v.y = bf2f(uv.y);
            v.z = bf2f(uv.z);
            v.w = bf2f(uv.w);
        }
        v.x = fmaxf(v.x * a1[k] + s1[k], 0.f);
        v.y = fmaxf(v.y * a1[k + 1] + s1[k + 1], 0.f);
        v.z = fmaxf(v.z * a1[k + 2] + s1[k + 2], 0.f);
        v.w = fmaxf(v.w * a1[k + 3] + s1[k + 3], 0.f);
        *(float4*)&zs[off] = v;
    }
    for (int idx = t; idx < 1024; idx += 256) {
        int off = idx * 4;
        *(float4*)&wsm[off] = *(const float4*)&w[off];
    }
    __syncthreads();
    int lane = t & 63, wid = t >> 6;
    float bv = bias[lane];
    float ssum = 0.f, ssq = 0.f;
    for (int j = 0; j < 8; ++j) {
        int r = wid * 8 + j;
        float acc = 0.f;
#pragma unroll
        for (int k = 0; k < 64; k += 4) {
            float4 zv = *(const float4*)&zs[r * 64 + k];
            acc += zv.x * wsm[(k + 0) * 64 + lane];
            acc += zv.y * wsm[(k + 1) * 64 + lane];
            acc += zv.z * wsm[(k + 2) * 64 + lane];
            acc += zv.w * wsm[(k + 3) * 64 + lane];
        }
        acc += bv;
        int gr = r0 + r;
        if (gr < NN) {
            out[gr * HC + lane] = f2bf(acc);
            ssum += acc;
            ssq += acc * acc;
        }
    }
    red[t] = ssum;
    __syncthreads();
    if (wid == 0) {
        float ts = red[lane] + red[64 + lane] + red[128 + lane] + red[192 + lane];
        atomicAdd(&statsOut[lane], ts);
    }
    __syncthreads();
    red[t] = ssq;
    __syncthreads();
    if (wid == 0) {
        float t2 = red[lane] + red[64 + lane] + red[128 + lane] + red[192 + lane];
        atomicAdd(&statsOut[64 + lane], t2);
    }
}

// ---------------- last-layer gdesc (BN2+ReLU, segmented sum, no h write) ----------------
#define CHK 16
__global__ void gdesc_last_kernel(const bf16_t* __restrict__ u, const float* __restrict__ stats,
                                  const float* __restrict__ g, const float* __restrict__ b,
                                  const int* __restrict__ batch, float* __restrict__ gdesc,
                                  int layer) {
    int lane = threadIdx.x & 63;
    int wid = threadIdx.x >> 6;
    int i0 = (blockIdx.x * 4 + wid) * CHK;
    if (i0 >= NN) return;
    float mu = stats[lane] * (1.0f / NN);
    float var = stats[64 + lane] * (1.0f / NN) - mu * mu;
    float a = g[lane] * rsqrtf(var + BN_EPS);
    float s = b[lane] - mu * a;
    int col = 1 + layer * HC + lane;
    float acc = 0.f;
    int cur = -1;
    int iend = i0 + CHK;
    if (iend > NN) iend = NN;
    for (int i = i0; i < iend; ++i) {
        int gid = batch[i];
        if (gid != cur) {
            if (cur >= 0) atomicAdd(&gdesc[cur * GD_COLS + col], acc);
            cur = gid;
            acc = 0.f;
        }
        acc += fmaxf(bf2f(u[i * HC + lane]) * a + s, 0.f);
    }
    if (cur >= 0) atomicAdd(&gdesc[cur * GD_COLS + col], acc);
}

__global__ void first_desc_kernel(const float* __restrict__ x, const int* __restrict__ batch,
                                  float* __restrict__ gdesc) {
    int i = blockIdx.x * blockDim.x + threadIdx.x;
    if (i < NN) atomicAdd(&gdesc[batch[i] * GD_COLS], x[i]);
}

__global__ void final_gemm_kernel(const float* __restrict__ gdesc, const float* __restrict__ lw,
                                  const float* __restrict__ lb, float* __restrict__ out) {
    int g = blockIdx.x;
    int lane = threadIdx.x;  // 64
    float a0 = 0.f, a1 = 0.f;
    for (int j = lane; j < GD_COLS; j += 64) {
        float v = gdesc[g * GD_COLS + j];
        a0 += v * lw[j * 2 + 0];
        a1 += v * lw[j * 2 + 1];
    }
    for (int off = 32; off > 0; off >>= 1) {
        a0 += __shfl_down(a0, off);
        a1 += __shfl_down(a1, off);
    }
    if (lane == 0) {
        out[g * 2 + 0] = a0 + lb[0];
        out[g * 2 + 1] = a1 + lb[1];
    }
}

extern "C" void kernel_launch(void* const* d_in, const int* in_sizes, int n_in, void* d_out,
                              int out_size, void* d_ws, size_t ws_size, hipStream_t stream) {
    const float* x = (const float*)d_in[0];
    const int* ei = (const int*)d_in[1];
    const int* batch = (const int*)d_in[2];
    const float* w1_0 = (const float*)d_in[3];
    const float* w1_rest = (const float*)d_in[4];
    const float* b1 = (const float*)d_in[5];
    const float* gm = (const float*)d_in[6];
    const float* bm = (const float*)d_in[7];
    const float* w2 = (const float*)d_in[8];
    const float* b2 = (const float*)d_in[9];
    const float* go = (const float*)d_in[10];
    const float* bo = (const float*)d_in[11];
    const float* lw = (const float*)d_in[12];
    const float* lb = (const float*)d_in[13];
    float* out = (float*)d_out;

    float* stats = (float*)d_ws;                     // NL*256
    float* gdesc = stats + NL * 256;                 // NG*321
    bf16_t* ybuf = (bf16_t*)(gdesc + (size_t)NG * GD_COLS + 64);  // NN*64 bf16
    bf16_t* ubuf = ybuf + (size_t)NN * HC;           // NN*64 bf16
    int* row_start = (int*)(ubuf + (size_t)NN * HC); // NN+1
    int* cursor = row_start + NN + 1;                // NN (also counts)
    int* tile_sums = cursor + NN;                    // 256
    int* ssrc = tile_sums + 256;                     // NE

    hipMemsetAsync(stats, 0, (NL * 256 + NG * GD_COLS) * sizeof(float), stream);
    hipMemsetAsync(cursor, 0, NN * sizeof(int), stream);  // counts

    // ---- CSR build (once; edges constant across layers) ----
    hist_kernel<<<(NE + 255) / 256, 256, 0, stream>>>(ei, cursor);
    scan_a_kernel<<<NT, 256, 0, stream>>>(cursor, row_start, tile_sums);
    scan_b_kernel<<<1, 256, 0, stream>>>(tile_sums);
    scan_c_kernel<<<NT, 256, 0, stream>>>(row_start, tile_sums, cursor);
    scatter_kernel<<<(NE + 255) / 256, 256, 0, stream>>>(ei, cursor, ssrc);

    // ---- layer 0 ----
    layer0_kernel<<<(NN + 63) / 64, 256, 0, stream>>>(x, row_start, ssrc, w1_0, b1, ybuf, stats);
    gemm64_norm_kernel<<<(NN + 31) / 32, 256, 0, stream>>>(ybuf, w2, b2, stats, gm, bm, ubuf,
                                                           stats + 128);

    // ---- layers 1..4 (K1 applies BN2 of prev layer + gdesc of prev layer) ----
    for (int l = 1; l < NL; ++l) {
        float* st1 = stats + l * 256;
        float* st2 = st1 + 128;
        float* stPrev = stats + (l - 1) * 256 + 128;
        gather_gemm_kernel<<<(NN + 31) / 32, 256, 0, stream>>>(
            ubuf, stPrev, go + (l - 1) * HC, bo + (l - 1) * HC, row_start, ssrc,
            w1_rest + (size_t)(l - 1) * HC * HC, b1 + l * HC, batch, gdesc, l - 1, ybuf, st1);
        gemm64_norm_kernel<<<(NN + 31) / 32, 256, 0, stream>>>(
            ybuf, w2 + (size_t)l * HC * HC, b2 + l * HC, st1, gm + l * HC, bm + l * HC, ubuf, st2);
    }

    gdesc_last_kernel<<<(NN + 4 * CHK - 1) / (4 * CHK), 256, 0, stream>>>(
        ubuf, stats + 4 * 256 + 128, go + 4 * HC, bo + 4 * HC, batch, gdesc, 4);
    first_desc_kernel<<<(NN + 255) / 256, 256, 0, stream>>>(x, batch, gdesc);
    final_gemm_kernel<<<NG, 64, 0, stream>>>(gdesc, lw, lb, out);
}

// Round 6
// 810.911 us; speedup vs baseline: 2.2331x; 1.1162x over previous
//
#include <hip/hip_runtime.h>

#define NN 50000
#define NE 800000
#define NG 512
#define HC 64
#define NL 5
#define GD_COLS 321
#define BN_EPS 1e-5f
#define NT 196  // scan tiles of 256 covering NN

typedef unsigned short bf16_t;

static __device__ __forceinline__ bf16_t f2bf(float f) {
    unsigned u = __float_as_uint(f);
    unsigned r = (u + 0x7FFFu + ((u >> 16) & 1u)) >> 16;
    return (bf16_t)r;
}
static __device__ __forceinline__ float bf2f(bf16_t h) {
    return __uint_as_float(((unsigned)h) << 16);
}

// ---------------- CSR build (edges sorted by dst), once per call ----------------

__global__ void hist_kernel(const int* __restrict__ ei, int* __restrict__ counts) {
    int e = blockIdx.x * blockDim.x + threadIdx.x;
    if (e < NE) atomicAdd(&counts[ei[NE + e]], 1);
}

__global__ void scan_a_kernel(const int* __restrict__ counts, int* __restrict__ row_start,
                              int* __restrict__ tile_sums) {
    __shared__ int sh[256];
    int t = threadIdx.x;
    int i = blockIdx.x * 256 + t;
    int c = (i < NN) ? counts[i] : 0;
    sh[t] = c;
    __syncthreads();
    for (int ofs = 1; ofs < 256; ofs <<= 1) {
        int v = (t >= ofs) ? sh[t - ofs] : 0;
        __syncthreads();
        sh[t] += v;
        __syncthreads();
    }
    if (i < NN) row_start[i] = sh[t] - c;
    if (t == 255) tile_sums[blockIdx.x] = sh[255];
}

__global__ void scan_b_kernel(int* __restrict__ tile_sums) {
    __shared__ int sh[256];
    int t = threadIdx.x;
    int v = (t < NT) ? tile_sums[t] : 0;
    sh[t] = v;
    __syncthreads();
    for (int ofs = 1; ofs < 256; ofs <<= 1) {
        int u = (t >= ofs) ? sh[t - ofs] : 0;
        __syncthreads();
        sh[t] += u;
        __syncthreads();
    }
    if (t < NT) tile_sums[t] = sh[t] - v;
}

__global__ void scan_c_kernel(int* __restrict__ row_start, const int* __restrict__ tile_sums,
                              int* __restrict__ cursor) {
    int i = blockIdx.x * 256 + threadIdx.x;
    if (i < NN) {
        int v = row_start[i] + tile_sums[blockIdx.x];
        row_start[i] = v;
        cursor[i] = v;
    }
    if (i == 0) row_start[NN] = NE;
}

__global__ void scatter_kernel(const int* __restrict__ ei, int* __restrict__ cursor,
                               int* __restrict__ ssrc) {
    int e = blockIdx.x * blockDim.x + threadIdx.x;
    if (e < NE) {
        int d = ei[NE + e];
        int pos = atomicAdd(&cursor[d], 1);
        ssrc[pos] = ei[e];
    }
}

// ---------------- layer 0: fused gather0 + rank-1 expand + stats ----------------
__global__ __launch_bounds__(256) void layer0_kernel(const float* __restrict__ x,
                                                     const int* __restrict__ row_start,
                                                     const int* __restrict__ ssrc,
                                                     const float* __restrict__ w,
                                                     const float* __restrict__ bias,
                                                     bf16_t* __restrict__ y,
                                                     float* __restrict__ stats) {
    __shared__ float z0s[64];
    int t = threadIdx.x, lane = t & 63, wid = t >> 6;
    int r0 = blockIdx.x * 64;
    if (t < 64) {
        int i = r0 + t;
        float acc = 0.f;
        if (i < NN) {
            acc = x[i];
            int p = row_start[i], pb = row_start[i + 1];
            for (; p + 4 <= pb; p += 4) {
                float v0 = x[ssrc[p]], v1 = x[ssrc[p + 1]];
                float v2 = x[ssrc[p + 2]], v3 = x[ssrc[p + 3]];
                acc += (v0 + v1) + (v2 + v3);
            }
            for (; p < pb; ++p) acc += x[ssrc[p]];
        }
        z0s[t] = acc;
    }
    __syncthreads();
    float wv = w[lane], bv = bias[lane];
    float s = 0.f, s2 = 0.f;
    for (int j = 0; j < 16; ++j) {
        int r = r0 + wid * 16 + j;
        if (r < NN) {
            float v = z0s[wid * 16 + j] * wv + bv;
            y[r * HC + lane] = f2bf(v);
            s += v;
            s2 += v * v;
        }
    }
    __shared__ float ls[256], ls2[256];
    ls[t] = s;
    ls2[t] = s2;
    __syncthreads();
    if (wid == 0) {
        float ts = ls[lane] + ls[64 + lane] + ls[128 + lane] + ls[192 + lane];
        float t2 = ls2[lane] + ls2[64 + lane] + ls2[128 + lane] + ls2[192 + lane];
        atomicAdd(&stats[lane], ts);
        atomicAdd(&stats[64 + lane], t2);
    }
}

// ---------------- K1: BN2(prev)+ReLU fused gather + gdesc(prev) + GEMM1 + stats1 --------
// Phase A (lane=channel): self terms h=relu(bn(u)) into zs + segmented gdesc.
// Phase B (16-lane groups, ushort4): edge gather, 8 edges in flight per group.
// Phase C (lane=channel): 32x64 @ 64x64 GEMM + stats.
__global__ __launch_bounds__(256) void gather_gemm_kernel(
    const bf16_t* __restrict__ u, const float* __restrict__ statsPrev,
    const float* __restrict__ gPrev, const float* __restrict__ bPrev,
    const int* __restrict__ row_start, const int* __restrict__ ssrc,
    const float* __restrict__ w, const float* __restrict__ bias, const int* __restrict__ batch,
    float* __restrict__ gdesc, int layerPrev, bf16_t* __restrict__ out,
    float* __restrict__ statsOut) {
    __shared__ float zs[32 * 64];
    __shared__ float wsm[64 * 64];
    __shared__ float a1[64], s1[64];
    __shared__ float red[256];
    int t = threadIdx.x, lane = t & 63, wid = t >> 6;
    int r0 = blockIdx.x * 32;
    if (t < 64) {
        float mu = statsPrev[t] * (1.0f / NN);
        float var = statsPrev[64 + t] * (1.0f / NN) - mu * mu;
        float a = gPrev[t] * rsqrtf(var + BN_EPS);
        a1[t] = a;
        s1[t] = bPrev[t] - mu * a;
    }
    for (int idx = t; idx < 1024; idx += 256)
        *(float4*)&wsm[idx * 4] = *(const float4*)&w[idx * 4];
    __syncthreads();
    // ---- Phase A: self terms + segmented gdesc (lane = channel) ----
    {
        float av = a1[lane], sv = s1[lane];
        int col = 1 + layerPrev * HC + lane;
        float gacc = 0.f;
        int cur = -1;
        for (int j = 0; j < 8; ++j) {
            int lr = wid * 8 + j, gr = r0 + lr;
            float hv = 0.f;
            if (gr < NN) {
                hv = fmaxf(bf2f(u[gr * HC + lane]) * av + sv, 0.f);
                int gid = batch[gr];
                if (gid != cur) {
                    if (cur >= 0) atomicAdd(&gdesc[cur * GD_COLS + col], gacc);
                    cur = gid;
                    gacc = 0.f;
                }
                gacc += hv;
            }
            zs[lr * 64 + lane] = hv;
        }
        if (cur >= 0) atomicAdd(&gdesc[cur * GD_COLS + col], gacc);
    }
    __syncthreads();
    // ---- Phase B: edge gather, 16-lane groups, ushort4, 8 edges in flight ----
    {
        int li = lane & 15;
        int gq = lane >> 4;
        float4 av4 = *(const float4*)&a1[li * 4];
        float4 sv4 = *(const float4*)&s1[li * 4];
        for (int half = 0; half < 2; ++half) {
            int lr = wid * 8 + gq + half * 4;
            int n = r0 + lr;
            int pa = 0, pb = 0;
            if (n < NN) {
                pa = row_start[n];
                pb = row_start[n + 1];
            }
            float4 acc = make_float4(0.f, 0.f, 0.f, 0.f);
            for (int p = pa; p < pb; p += 8) {
                int idx[8];
#pragma unroll
                for (int e = 0; e < 8; ++e) {
                    int pe = p + e;
                    idx[e] = ssrc[pe < pb ? pe : pb - 1];
                }
                ushort4 rv[8];
#pragma unroll
                for (int e = 0; e < 8; ++e)
                    rv[e] = *(const ushort4*)&u[(size_t)idx[e] * HC + li * 4];
#pragma unroll
                for (int e = 0; e < 8; ++e) {
                    float vx = fmaxf(bf2f(rv[e].x) * av4.x + sv4.x, 0.f);
                    float vy = fmaxf(bf2f(rv[e].y) * av4.y + sv4.y, 0.f);
                    float vz = fmaxf(bf2f(rv[e].z) * av4.z + sv4.z, 0.f);
                    float vw = fmaxf(bf2f(rv[e].w) * av4.w + sv4.w, 0.f);
                    if (p + e < pb) {
                        acc.x += vx;
                        acc.y += vy;
                        acc.z += vz;
                        acc.w += vw;
                    }
                }
            }
            // zs row owned by this group only — plain RMW, no atomics
            float4 z = *(float4*)&zs[lr * 64 + li * 4];
            z.x += acc.x;
            z.y += acc.y;
            z.z += acc.z;
            z.w += acc.w;
            *(float4*)&zs[lr * 64 + li * 4] = z;
        }
    }
    __syncthreads();
    // ---- Phase C: GEMM1 + stats1 (lane = channel) ----
    float bv = bias[lane];
    float ssum = 0.f, ssq = 0.f;
    for (int j = 0; j < 8; ++j) {
        int r = wid * 8 + j;
        float acc = 0.f;
#pragma unroll
        for (int k = 0; k < 64; k += 4) {
            float4 zv = *(const float4*)&zs[r * 64 + k];
            acc += zv.x * wsm[(k + 0) * 64 + lane];
            acc += zv.y * wsm[(k + 1) * 64 + lane];
            acc += zv.z * wsm[(k + 2) * 64 + lane];
            acc += zv.w * wsm[(k + 3) * 64 + lane];
        }
        acc += bv;
        int gr = r0 + r;
        if (gr < NN) {
            out[gr * HC + lane] = f2bf(acc);
            ssum += acc;
            ssq += acc * acc;
        }
    }
    red[t] = ssum;
    __syncthreads();
    if (wid == 0) {
        float ts = red[lane] + red[64 + lane] + red[128 + lane] + red[192 + lane];
        atomicAdd(&statsOut[lane], ts);
    }
    __syncthreads();
    red[t] = ssq;
    __syncthreads();
    if (wid == 0) {
        float t2 = red[lane] + red[64 + lane] + red[128 + lane] + red[192 + lane];
        atomicAdd(&statsOut[64 + lane], t2);
    }
}

// ---------------- K2: BN1+ReLU fused GEMM2 + stats2 (32 rows/block, bf16 io) ----------------
__global__ __launch_bounds__(256) void gemm64_norm_kernel(
    const bf16_t* __restrict__ in, const float* __restrict__ w, const float* __restrict__ bias,
    const float* __restrict__ statsIn, const float* __restrict__ gIn,
    const float* __restrict__ bIn, bf16_t* __restrict__ out, float* __restrict__ statsOut) {
    __shared__ float zs[32 * 64];
    __shared__ float wsm[64 * 64];
    __shared__ float a1[64], s1[64];
    __shared__ float red[256];
    int t = threadIdx.x;
    if (t < 64) {
        float mu = statsIn[t] * (1.0f / NN);
        float var = statsIn[64 + t] * (1.0f / NN) - mu * mu;
        float a = gIn[t] * rsqrtf(var + BN_EPS);
        a1[t] = a;
        s1[t] = bIn[t] - mu * a;
    }
    __syncthreads();
    int r0 = blockIdx.x * 32;
    for (int idx = t; idx < 512; idx += 256) {
        int off = idx * 4;
        int r = r0 + (off >> 6);
        int k = off & 63;
        float4 v = make_float4(0.f, 0.f, 0.f, 0.f);
        if (r < NN) {
            ushort4 uv = *(const ushort4*)&in[r * HC + k];
            v.x = bf2f(uv.x);
            v.y = bf2f(uv.y);
            v.z = bf2f(uv.z);
            v.w = bf2f(uv.w);
        }
        v.x = fmaxf(v.x * a1[k] + s1[k], 0.f);
        v.y = fmaxf(v.y * a1[k + 1] + s1[k + 1], 0.f);
        v.z = fmaxf(v.z * a1[k + 2] + s1[k + 2], 0.f);
        v.w = fmaxf(v.w * a1[k + 3] + s1[k + 3], 0.f);
        *(float4*)&zs[off] = v;
    }
    for (int idx = t; idx < 1024; idx += 256) {
        int off = idx * 4;
        *(float4*)&wsm[off] = *(const float4*)&w[off];
    }
    __syncthreads();
    int lane = t & 63, wid = t >> 6;
    float bv = bias[lane];
    float ssum = 0.f, ssq = 0.f;
    for (int j = 0; j < 8; ++j) {
        int r = wid * 8 + j;
        float acc = 0.f;
#pragma unroll
        for (int k = 0; k < 64; k += 4) {
            float4 zv = *(const float4*)&zs[r * 64 + k];
            acc += zv.x * wsm[(k + 0) * 64 + lane];
            acc += zv.y * wsm[(k + 1) * 64 + lane];
            acc += zv.z * wsm[(k + 2) * 64 + lane];
            acc += zv.w * wsm[(k + 3) * 64 + lane];
        }
        acc += bv;
        int gr = r0 + r;
        if (gr < NN) {
            out[gr * HC + lane] = f2bf(acc);
            ssum += acc;
            ssq += acc * acc;
        }
    }
    red[t] = ssum;
    __syncthreads();
    if (wid == 0) {
        float ts = red[lane] + red[64 + lane] + red[128 + lane] + red[192 + lane];
        atomicAdd(&statsOut[lane], ts);
    }
    __syncthreads();
    red[t] = ssq;
    __syncthreads();
    if (wid == 0) {
        float t2 = red[lane] + red[64 + lane] + red[128 + lane] + red[192 + lane];
        atomicAdd(&statsOut[64 + lane], t2);
    }
}

// ---------------- last-layer gdesc (BN2+ReLU, segmented sum, no h write) ----------------
#define CHK 16
__global__ void gdesc_last_kernel(const bf16_t* __restrict__ u, const float* __restrict__ stats,
                                  const float* __restrict__ g, const float* __restrict__ b,
                                  const int* __restrict__ batch, float* __restrict__ gdesc,
                                  int layer) {
    int lane = threadIdx.x & 63;
    int wid = threadIdx.x >> 6;
    int i0 = (blockIdx.x * 4 + wid) * CHK;
    if (i0 >= NN) return;
    float mu = stats[lane] * (1.0f / NN);
    float var = stats[64 + lane] * (1.0f / NN) - mu * mu;
    float a = g[lane] * rsqrtf(var + BN_EPS);
    float s = b[lane] - mu * a;
    int col = 1 + layer * HC + lane;
    float acc = 0.f;
    int cur = -1;
    int iend = i0 + CHK;
    if (iend > NN) iend = NN;
    for (int i = i0; i < iend; ++i) {
        int gid = batch[i];
        if (gid != cur) {
            if (cur >= 0) atomicAdd(&gdesc[cur * GD_COLS + col], acc);
            cur = gid;
            acc = 0.f;
        }
        acc += fmaxf(bf2f(u[i * HC + lane]) * a + s, 0.f);
    }
    if (cur >= 0) atomicAdd(&gdesc[cur * GD_COLS + col], acc);
}

__global__ void first_desc_kernel(const float* __restrict__ x, const int* __restrict__ batch,
                                  float* __restrict__ gdesc) {
    int i = blockIdx.x * blockDim.x + threadIdx.x;
    if (i < NN) atomicAdd(&gdesc[batch[i] * GD_COLS], x[i]);
}

__global__ void final_gemm_kernel(const float* __restrict__ gdesc, const float* __restrict__ lw,
                                  const float* __restrict__ lb, float* __restrict__ out) {
    int g = blockIdx.x;
    int lane = threadIdx.x;  // 64
    float a0 = 0.f, a1 = 0.f;
    for (int j = lane; j < GD_COLS; j += 64) {
        float v = gdesc[g * GD_COLS + j];
        a0 += v * lw[j * 2 + 0];
        a1 += v * lw[j * 2 + 1];
    }
    for (int off = 32; off > 0; off >>= 1) {
        a0 += __shfl_down(a0, off);
        a1 += __shfl_down(a1, off);
    }
    if (lane == 0) {
        out[g * 2 + 0] = a0 + lb[0];
        out[g * 2 + 1] = a1 + lb[1];
    }
}

extern "C" void kernel_launch(void* const* d_in, const int* in_sizes, int n_in, void* d_out,
                              int out_size, void* d_ws, size_t ws_size, hipStream_t stream) {
    const float* x = (const float*)d_in[0];
    const int* ei = (const int*)d_in[1];
    const int* batch = (const int*)d_in[2];
    const float* w1_0 = (const float*)d_in[3];
    const float* w1_rest = (const float*)d_in[4];
    const float* b1 = (const float*)d_in[5];
    const float* gm = (const float*)d_in[6];
    const float* bm = (const float*)d_in[7];
    const float* w2 = (const float*)d_in[8];
    const float* b2 = (const float*)d_in[9];
    const float* go = (const float*)d_in[10];
    const float* bo = (const float*)d_in[11];
    const float* lw = (const float*)d_in[12];
    const float* lb = (const float*)d_in[13];
    float* out = (float*)d_out;

    float* stats = (float*)d_ws;                     // NL*256
    float* gdesc = stats + NL * 256;                 // NG*321
    bf16_t* ybuf = (bf16_t*)(gdesc + (size_t)NG * GD_COLS + 64);  // NN*64 bf16
    bf16_t* ubuf = ybuf + (size_t)NN * HC;           // NN*64 bf16
    int* row_start = (int*)(ubuf + (size_t)NN * HC); // NN+1
    int* cursor = row_start + NN + 1;                // NN (also counts)
    int* tile_sums = cursor + NN;                    // 256
    int* ssrc = tile_sums + 256;                     // NE

    hipMemsetAsync(stats, 0, (NL * 256 + NG * GD_COLS) * sizeof(float), stream);
    hipMemsetAsync(cursor, 0, NN * sizeof(int), stream);  // counts

    // ---- CSR build (once; edges constant across layers) ----
    hist_kernel<<<(NE + 255) / 256, 256, 0, stream>>>(ei, cursor);
    scan_a_kernel<<<NT, 256, 0, stream>>>(cursor, row_start, tile_sums);
    scan_b_kernel<<<1, 256, 0, stream>>>(tile_sums);
    scan_c_kernel<<<NT, 256, 0, stream>>>(row_start, tile_sums, cursor);
    scatter_kernel<<<(NE + 255) / 256, 256, 0, stream>>>(ei, cursor, ssrc);

    // ---- layer 0 ----
    layer0_kernel<<<(NN + 63) / 64, 256, 0, stream>>>(x, row_start, ssrc, w1_0, b1, ybuf, stats);
    gemm64_norm_kernel<<<(NN + 31) / 32, 256, 0, stream>>>(ybuf, w2, b2, stats, gm, bm, ubuf,
                                                           stats + 128);

    // ---- layers 1..4 (K1 applies BN2 of prev layer + gdesc of prev layer) ----
    for (int l = 1; l < NL; ++l) {
        float* st1 = stats + l * 256;
        float* st2 = st1 + 128;
        float* stPrev = stats + (l - 1) * 256 + 128;
        gather_gemm_kernel<<<(NN + 31) / 32, 256, 0, stream>>>(
            ubuf, stPrev, go + (l - 1) * HC, bo + (l - 1) * HC, row_start, ssrc,
            w1_rest + (size_t)(l - 1) * HC * HC, b1 + l * HC, batch, gdesc, l - 1, ybuf, st1);
        gemm64_norm_kernel<<<(NN + 31) / 32, 256, 0, stream>>>(
            ybuf, w2 + (size_t)l * HC * HC, b2 + l * HC, st1, gm + l * HC, bm + l * HC, ubuf, st2);
    }

    gdesc_last_kernel<<<(NN + 4 * CHK - 1) / (4 * CHK), 256, 0, stream>>>(
        ubuf, stats + 4 * 256 + 128, go + 4 * HC, bo + 4 * HC, batch, gdesc, 4);
    first_desc_kernel<<<(NN + 255) / 256, 256, 0, stream>>>(x, batch, gdesc);
    final_gemm_kernel<<<NG, 64, 0, stream>>>(gdesc, lw, lb, out);
}

// Round 7
// 762.232 us; speedup vs baseline: 2.3757x; 1.0639x over previous
//
#include <hip/hip_runtime.h>

#define NN 50000
#define NE 800000
#define NG 512
#define HC 64
#define NL 5
#define GD_COLS 321
#define BN_EPS 1e-5f
#define NT 196  // scan tiles of 256 covering NN

typedef unsigned short bf16_t;

static __device__ __forceinline__ bf16_t f2bf(float f) {
    unsigned u = __float_as_uint(f);
    unsigned r = (u + 0x7FFFu + ((u >> 16) & 1u)) >> 16;
    return (bf16_t)r;
}
static __device__ __forceinline__ float bf2f(bf16_t h) {
    return __uint_as_float(((unsigned)h) << 16);
}
static __device__ __forceinline__ float bflo(unsigned w) {  // low bf16 of packed pair
    return __uint_as_float(w << 16);
}
static __device__ __forceinline__ float bfhi(unsigned w) {  // high bf16 of packed pair
    return __uint_as_float(w & 0xffff0000u);
}

// ---------------- CSR build (edges sorted by dst), once per call ----------------

__global__ void hist_kernel(const int* __restrict__ ei, int* __restrict__ counts) {
    int e = blockIdx.x * blockDim.x + threadIdx.x;
    if (e < NE) atomicAdd(&counts[ei[NE + e]], 1);
}

__global__ void scan_a_kernel(const int* __restrict__ counts, int* __restrict__ row_start,
                              int* __restrict__ tile_sums) {
    __shared__ int sh[256];
    int t = threadIdx.x;
    int i = blockIdx.x * 256 + t;
    int c = (i < NN) ? counts[i] : 0;
    sh[t] = c;
    __syncthreads();
    for (int ofs = 1; ofs < 256; ofs <<= 1) {
        int v = (t >= ofs) ? sh[t - ofs] : 0;
        __syncthreads();
        sh[t] += v;
        __syncthreads();
    }
    if (i < NN) row_start[i] = sh[t] - c;
    if (t == 255) tile_sums[blockIdx.x] = sh[255];
}

__global__ void scan_b_kernel(int* __restrict__ tile_sums) {
    __shared__ int sh[256];
    int t = threadIdx.x;
    int v = (t < NT) ? tile_sums[t] : 0;
    sh[t] = v;
    __syncthreads();
    for (int ofs = 1; ofs < 256; ofs <<= 1) {
        int u = (t >= ofs) ? sh[t - ofs] : 0;
        __syncthreads();
        sh[t] += u;
        __syncthreads();
    }
    if (t < NT) tile_sums[t] = sh[t] - v;
}

__global__ void scan_c_kernel(int* __restrict__ row_start, const int* __restrict__ tile_sums,
                              int* __restrict__ cursor) {
    int i = blockIdx.x * 256 + threadIdx.x;
    if (i < NN) {
        int v = row_start[i] + tile_sums[blockIdx.x];
        row_start[i] = v;
        cursor[i] = v;
    }
    if (i == 0) row_start[NN] = NE;
}

__global__ void scatter_kernel(const int* __restrict__ ei, int* __restrict__ cursor,
                               int* __restrict__ ssrc) {
    int e = blockIdx.x * blockDim.x + threadIdx.x;
    if (e < NE) {
        int d = ei[NE + e];
        int pos = atomicAdd(&cursor[d], 1);
        ssrc[pos] = ei[e];
    }
}

// ---------------- layer 0: fused gather0 + rank-1 expand + stats ----------------
__global__ __launch_bounds__(256) void layer0_kernel(const float* __restrict__ x,
                                                     const int* __restrict__ row_start,
                                                     const int* __restrict__ ssrc,
                                                     const float* __restrict__ w,
                                                     const float* __restrict__ bias,
                                                     bf16_t* __restrict__ y,
                                                     float* __restrict__ stats) {
    __shared__ float z0p[256];
    __shared__ float z0s[64];
    int t = threadIdx.x, lane = t & 63, wid = t >> 6;
    int r0 = blockIdx.x * 64;
    // phase 1: all 256 threads; 4 sub-slices per node
    {
        int node = t >> 2, sub = t & 3;
        int i = r0 + node;
        float acc = 0.f;
        if (i < NN) {
            int pa = row_start[i], pb = row_start[i + 1];
            for (int p = pa + sub; p < pb; p += 4) acc += x[ssrc[p]];
            if (sub == 0) acc += x[i];
        }
        z0p[t] = acc;
    }
    __syncthreads();
    if (t < 64) z0s[t] = z0p[4 * t] + z0p[4 * t + 1] + z0p[4 * t + 2] + z0p[4 * t + 3];
    __syncthreads();
    float wv = w[lane], bv = bias[lane];
    float s = 0.f, s2 = 0.f;
    for (int j = 0; j < 16; ++j) {
        int r = r0 + wid * 16 + j;
        if (r < NN) {
            float v = z0s[wid * 16 + j] * wv + bv;
            y[r * HC + lane] = f2bf(v);
            s += v;
            s2 += v * v;
        }
    }
    __shared__ float ls[256], ls2[256];
    ls[t] = s;
    ls2[t] = s2;
    __syncthreads();
    if (wid == 0) {
        float ts = ls[lane] + ls[64 + lane] + ls[128 + lane] + ls[192 + lane];
        float t2 = ls2[lane] + ls2[64 + lane] + ls2[128 + lane] + ls2[192 + lane];
        atomicAdd(&stats[lane], ts);
        atomicAdd(&stats[64 + lane], t2);
    }
}

// ---------------- K1: BN2(prev)+ReLU fused gather + gdesc(prev) + GEMM1 + stats1 --------
// After the staging barrier the kernel is wave-local (rows wid*8..wid*8+7):
//   Phase A (lane=channel): self terms into zs + segmented gdesc.
//   Phase B (8-lane groups, uint4=8ch): edge gather, 8 rows in flight per instr.
//   Phase C (lane=out channel): 32x64 @ 64x64 GEMM (bf16 transposed weights) + stats.
__global__ __launch_bounds__(256) void gather_gemm_kernel(
    const bf16_t* __restrict__ u, const float* __restrict__ statsPrev,
    const float* __restrict__ gPrev, const float* __restrict__ bPrev,
    const int* __restrict__ row_start, const int* __restrict__ ssrc,
    const float* __restrict__ w, const float* __restrict__ bias, const int* __restrict__ batch,
    float* __restrict__ gdesc, int layerPrev, bf16_t* __restrict__ out,
    float* __restrict__ statsOut) {
    __shared__ float zs[32 * 64];
    __shared__ bf16_t wsmT[64 * 68];  // [outCol][k], pad 68: 8B-aligned rows, bank-clean
    __shared__ float a1[64], s1[64];
    __shared__ float red[256];
    int t = threadIdx.x, lane = t & 63, wid = t >> 6;
    int r0 = blockIdx.x * 32;
    if (t < 64) {
        float mu = statsPrev[t] * (1.0f / NN);
        float var = statsPrev[64 + t] * (1.0f / NN) - mu * mu;
        float a = gPrev[t] * rsqrtf(var + BN_EPS);
        a1[t] = a;
        s1[t] = bPrev[t] - mu * a;
    }
    for (int idx = t; idx < 4096; idx += 256) {
        int k = idx >> 6, c = idx & 63;
        wsmT[c * 68 + k] = f2bf(w[idx]);  // w[k*64+c], coalesced read
    }
    __syncthreads();
    // ---- Phase A: self terms + segmented gdesc (lane = channel) ----
    {
        float av = a1[lane], sv = s1[lane];
        int col = 1 + layerPrev * HC + lane;
        float gacc = 0.f;
        int cur = -1;
        for (int j = 0; j < 8; ++j) {
            int lr = wid * 8 + j, gr = r0 + lr;
            float hv = 0.f;
            if (gr < NN) {
                hv = fmaxf(bf2f(u[gr * HC + lane]) * av + sv, 0.f);
                int gid = batch[gr];
                if (gid != cur) {
                    if (cur >= 0) atomicAdd(&gdesc[cur * GD_COLS + col], gacc);
                    cur = gid;
                    gacc = 0.f;
                }
                gacc += hv;
            }
            zs[lr * 64 + lane] = hv;
        }
        if (cur >= 0) atomicAdd(&gdesc[cur * GD_COLS + col], gacc);
    }
    // ---- Phase B: edge gather, 8-lane groups, uint4 (8 bf16 ch), 8 edges in flight ----
    // wave-local wrt phase A (same row partition) — no barrier needed
    {
        int li = lane & 7;   // channel block (8 channels)
        int gq = lane >> 3;  // row within wave's 8
        int lr = wid * 8 + gq;
        int n = r0 + lr;
        float a8[8], s8[8];
#pragma unroll
        for (int c = 0; c < 8; ++c) {
            a8[c] = a1[li * 8 + c];
            s8[c] = s1[li * 8 + c];
        }
        float acc[8];
#pragma unroll
        for (int c = 0; c < 8; ++c) acc[c] = 0.f;
        if (n < NN) {
            int pa = row_start[n], pb = row_start[n + 1];
            for (int p = pa; p < pb; p += 8) {
                int idx[8];
#pragma unroll
                for (int e = 0; e < 8; ++e) {
                    int pe = p + e;
                    idx[e] = ssrc[pe < pb ? pe : pb - 1];
                }
                uint4 rv[8];
#pragma unroll
                for (int e = 0; e < 8; ++e)
                    rv[e] = *(const uint4*)&u[(size_t)idx[e] * HC + li * 8];
#pragma unroll
                for (int e = 0; e < 8; ++e) {
                    float v0 = fmaxf(bflo(rv[e].x) * a8[0] + s8[0], 0.f);
                    float v1 = fmaxf(bfhi(rv[e].x) * a8[1] + s8[1], 0.f);
                    float v2 = fmaxf(bflo(rv[e].y) * a8[2] + s8[2], 0.f);
                    float v3 = fmaxf(bfhi(rv[e].y) * a8[3] + s8[3], 0.f);
                    float v4 = fmaxf(bflo(rv[e].z) * a8[4] + s8[4], 0.f);
                    float v5 = fmaxf(bfhi(rv[e].z) * a8[5] + s8[5], 0.f);
                    float v6 = fmaxf(bflo(rv[e].w) * a8[6] + s8[6], 0.f);
                    float v7 = fmaxf(bfhi(rv[e].w) * a8[7] + s8[7], 0.f);
                    if (p + e < pb) {
                        acc[0] += v0;
                        acc[1] += v1;
                        acc[2] += v2;
                        acc[3] += v3;
                        acc[4] += v4;
                        acc[5] += v5;
                        acc[6] += v6;
                        acc[7] += v7;
                    }
                }
            }
        }
        // exclusive (lr, li) ownership within the wave — plain RMW
        float4 z0v = *(float4*)&zs[lr * 64 + li * 8];
        z0v.x += acc[0];
        z0v.y += acc[1];
        z0v.z += acc[2];
        z0v.w += acc[3];
        *(float4*)&zs[lr * 64 + li * 8] = z0v;
        float4 z1v = *(float4*)&zs[lr * 64 + li * 8 + 4];
        z1v.x += acc[4];
        z1v.y += acc[5];
        z1v.z += acc[6];
        z1v.w += acc[7];
        *(float4*)&zs[lr * 64 + li * 8 + 4] = z1v;
    }
    // ---- Phase C: GEMM1 + stats1 (lane = out channel) — wave-local rows ----
    float bv = bias[lane];
    float ssum = 0.f, ssq = 0.f;
    for (int j = 0; j < 8; ++j) {
        int r = wid * 8 + j;
        float acc = 0.f;
#pragma unroll
        for (int k = 0; k < 64; k += 4) {
            float4 zv = *(const float4*)&zs[r * 64 + k];  // broadcast across lanes
            uint2 wv = *(const uint2*)&wsmT[lane * 68 + k];
            acc += zv.x * bflo(wv.x);
            acc += zv.y * bfhi(wv.x);
            acc += zv.z * bflo(wv.y);
            acc += zv.w * bfhi(wv.y);
        }
        acc += bv;
        int gr = r0 + r;
        if (gr < NN) {
            out[gr * HC + lane] = f2bf(acc);
            ssum += acc;
            ssq += acc * acc;
        }
    }
    red[t] = ssum;
    __syncthreads();
    if (wid == 0) {
        float ts = red[lane] + red[64 + lane] + red[128 + lane] + red[192 + lane];
        atomicAdd(&statsOut[lane], ts);
    }
    __syncthreads();
    red[t] = ssq;
    __syncthreads();
    if (wid == 0) {
        float t2 = red[lane] + red[64 + lane] + red[128 + lane] + red[192 + lane];
        atomicAdd(&statsOut[64 + lane], t2);
    }
}

// ---------------- K2: BN1+ReLU fused GEMM2 + stats2 (32 rows/block, bf16 io) ----------------
__global__ __launch_bounds__(256) void gemm64_norm_kernel(
    const bf16_t* __restrict__ in, const float* __restrict__ w, const float* __restrict__ bias,
    const float* __restrict__ statsIn, const float* __restrict__ gIn,
    const float* __restrict__ bIn, bf16_t* __restrict__ out, float* __restrict__ statsOut) {
    __shared__ float zs[32 * 64];
    __shared__ float wsm[64 * 64];
    __shared__ float a1[64], s1[64];
    __shared__ float red[256];
    int t = threadIdx.x;
    if (t < 64) {
        float mu = statsIn[t] * (1.0f / NN);
        float var = statsIn[64 + t] * (1.0f / NN) - mu * mu;
        float a = gIn[t] * rsqrtf(var + BN_EPS);
        a1[t] = a;
        s1[t] = bIn[t] - mu * a;
    }
    __syncthreads();
    int r0 = blockIdx.x * 32;
    for (int idx = t; idx < 512; idx += 256) {
        int off = idx * 4;
        int r = r0 + (off >> 6);
        int k = off & 63;
        float4 v = make_float4(0.f, 0.f, 0.f, 0.f);
        if (r < NN) {
            ushort4 uv = *(const ushort4*)&in[r * HC + k];
            v.x = bf2f(uv.x);
            v.y = bf2f(uv.y);
            v.z = bf2f(uv.z);
            v.w = bf2f(uv.w);
        }
        v.x = fmaxf(v.x * a1[k] + s1[k], 0.f);
        v.y = fmaxf(v.y * a1[k + 1] + s1[k + 1], 0.f);
        v.z = fmaxf(v.z * a1[k + 2] + s1[k + 2], 0.f);
        v.w = fmaxf(v.w * a1[k + 3] + s1[k + 3], 0.f);
        *(float4*)&zs[off] = v;
    }
    for (int idx = t; idx < 1024; idx += 256) {
        int off = idx * 4;
        *(float4*)&wsm[off] = *(const float4*)&w[off];
    }
    __syncthreads();
    int lane = t & 63, wid = t >> 6;
    float bv = bias[lane];
    float ssum = 0.f, ssq = 0.f;
    for (int j = 0; j < 8; ++j) {
        int r = wid * 8 + j;
        float acc = 0.f;
#pragma unroll
        for (int k = 0; k < 64; k += 4) {
            float4 zv = *(const float4*)&zs[r * 64 + k];
            acc += zv.x * wsm[(k + 0) * 64 + lane];
            acc += zv.y * wsm[(k + 1) * 64 + lane];
            acc += zv.z * wsm[(k + 2) * 64 + lane];
            acc += zv.w * wsm[(k + 3) * 64 + lane];
        }
        acc += bv;
        int gr = r0 + r;
        if (gr < NN) {
            out[gr * HC + lane] = f2bf(acc);
            ssum += acc;
            ssq += acc * acc;
        }
    }
    red[t] = ssum;
    __syncthreads();
    if (wid == 0) {
        float ts = red[lane] + red[64 + lane] + red[128 + lane] + red[192 + lane];
        atomicAdd(&statsOut[lane], ts);
    }
    __syncthreads();
    red[t] = ssq;
    __syncthreads();
    if (wid == 0) {
        float t2 = red[lane] + red[64 + lane] + red[128 + lane] + red[192 + lane];
        atomicAdd(&statsOut[64 + lane], t2);
    }
}

// ---------------- last-layer gdesc (BN2+ReLU, segmented sum, no h write) ----------------
#define CHK 16
__global__ void gdesc_last_kernel(const bf16_t* __restrict__ u, const float* __restrict__ stats,
                                  const float* __restrict__ g, const float* __restrict__ b,
                                  const int* __restrict__ batch, float* __restrict__ gdesc,
                                  int layer) {
    int lane = threadIdx.x & 63;
    int wid = threadIdx.x >> 6;
    int i0 = (blockIdx.x * 4 + wid) * CHK;
    if (i0 >= NN) return;
    float mu = stats[lane] * (1.0f / NN);
    float var = stats[64 + lane] * (1.0f / NN) - mu * mu;
    float a = g[lane] * rsqrtf(var + BN_EPS);
    float s = b[lane] - mu * a;
    int col = 1 + layer * HC + lane;
    float acc = 0.f;
    int cur = -1;
    int iend = i0 + CHK;
    if (iend > NN) iend = NN;
    for (int i = i0; i < iend; ++i) {
        int gid = batch[i];
        if (gid != cur) {
            if (cur >= 0) atomicAdd(&gdesc[cur * GD_COLS + col], acc);
            cur = gid;
            acc = 0.f;
        }
        acc += fmaxf(bf2f(u[i * HC + lane]) * a + s, 0.f);
    }
    if (cur >= 0) atomicAdd(&gdesc[cur * GD_COLS + col], acc);
}

__global__ void first_desc_kernel(const float* __restrict__ x, const int* __restrict__ batch,
                                  float* __restrict__ gdesc) {
    int i = blockIdx.x * blockDim.x + threadIdx.x;
    if (i < NN) atomicAdd(&gdesc[batch[i] * GD_COLS], x[i]);
}

__global__ void final_gemm_kernel(const float* __restrict__ gdesc, const float* __restrict__ lw,
                                  const float* __restrict__ lb, float* __restrict__ out) {
    int g = blockIdx.x;
    int lane = threadIdx.x;  // 64
    float a0 = 0.f, a1 = 0.f;
    for (int j = lane; j < GD_COLS; j += 64) {
        float v = gdesc[g * GD_COLS + j];
        a0 += v * lw[j * 2 + 0];
        a1 += v * lw[j * 2 + 1];
    }
    for (int off = 32; off > 0; off >>= 1) {
        a0 += __shfl_down(a0, off);
        a1 += __shfl_down(a1, off);
    }
    if (lane == 0) {
        out[g * 2 + 0] = a0 + lb[0];
        out[g * 2 + 1] = a1 + lb[1];
    }
}

extern "C" void kernel_launch(void* const* d_in, const int* in_sizes, int n_in, void* d_out,
                              int out_size, void* d_ws, size_t ws_size, hipStream_t stream) {
    const float* x = (const float*)d_in[0];
    const int* ei = (const int*)d_in[1];
    const int* batch = (const int*)d_in[2];
    const float* w1_0 = (const float*)d_in[3];
    const float* w1_rest = (const float*)d_in[4];
    const float* b1 = (const float*)d_in[5];
    const float* gm = (const float*)d_in[6];
    const float* bm = (const float*)d_in[7];
    const float* w2 = (const float*)d_in[8];
    const float* b2 = (const float*)d_in[9];
    const float* go = (const float*)d_in[10];
    const float* bo = (const float*)d_in[11];
    const float* lw = (const float*)d_in[12];
    const float* lb = (const float*)d_in[13];
    float* out = (float*)d_out;

    float* stats = (float*)d_ws;                     // NL*256
    float* gdesc = stats + NL * 256;                 // NG*321
    bf16_t* ybuf = (bf16_t*)(gdesc + (size_t)NG * GD_COLS + 64);  // NN*64 bf16
    bf16_t* ubuf = ybuf + (size_t)NN * HC;           // NN*64 bf16
    int* row_start = (int*)(ubuf + (size_t)NN * HC); // NN+1
    int* cursor = row_start + NN + 1;                // NN (also counts)
    int* tile_sums = cursor + NN;                    // 256
    int* ssrc = tile_sums + 256;                     // NE

    hipMemsetAsync(stats, 0, (NL * 256 + NG * GD_COLS) * sizeof(float), stream);
    hipMemsetAsync(cursor, 0, NN * sizeof(int), stream);  // counts

    // ---- CSR build (once; edges constant across layers) ----
    hist_kernel<<<(NE + 255) / 256, 256, 0, stream>>>(ei, cursor);
    scan_a_kernel<<<NT, 256, 0, stream>>>(cursor, row_start, tile_sums);
    scan_b_kernel<<<1, 256, 0, stream>>>(tile_sums);
    scan_c_kernel<<<NT, 256, 0, stream>>>(row_start, tile_sums, cursor);
    scatter_kernel<<<(NE + 255) / 256, 256, 0, stream>>>(ei, cursor, ssrc);

    // ---- layer 0 ----
    layer0_kernel<<<(NN + 63) / 64, 256, 0, stream>>>(x, row_start, ssrc, w1_0, b1, ybuf, stats);
    gemm64_norm_kernel<<<(NN + 31) / 32, 256, 0, stream>>>(ybuf, w2, b2, stats, gm, bm, ubuf,
                                                           stats + 128);

    // ---- layers 1..4 (K1 applies BN2 of prev layer + gdesc of prev layer) ----
    for (int l = 1; l < NL; ++l) {
        float* st1 = stats + l * 256;
        float* st2 = st1 + 128;
        float* stPrev = stats + (l - 1) * 256 + 128;
        gather_gemm_kernel<<<(NN + 31) / 32, 256, 0, stream>>>(
            ubuf, stPrev, go + (l - 1) * HC, bo + (l - 1) * HC, row_start, ssrc,
            w1_rest + (size_t)(l - 1) * HC * HC, b1 + l * HC, batch, gdesc, l - 1, ybuf, st1);
        gemm64_norm_kernel<<<(NN + 31) / 32, 256, 0, stream>>>(
            ybuf, w2 + (size_t)l * HC * HC, b2 + l * HC, st1, gm + l * HC, bm + l * HC, ubuf, st2);
    }

    gdesc_last_kernel<<<(NN + 4 * CHK - 1) / (4 * CHK), 256, 0, stream>>>(
        ubuf, stats + 4 * 256 + 128, go + 4 * HC, bo + 4 * HC, batch, gdesc, 4);
    first_desc_kernel<<<(NN + 255) / 256, 256, 0, stream>>>(x, batch, gdesc);
    final_gemm_kernel<<<NG, 64, 0, stream>>>(gdesc, lw, lb, out);
}

// Round 8
// 710.814 us; speedup vs baseline: 2.5476x; 1.0723x over previous
//
#include <hip/hip_runtime.h>

#define NN 50000
#define NE 800000
#define NG 512
#define HC 64
#define NL 5
#define GD_COLS 321
#define BN_EPS 1e-5f
#define NT 196  // scan tiles of 256 covering NN

typedef unsigned short bf16_t;

static __device__ __forceinline__ unsigned f2bfbits(float f) {
    unsigned u = __float_as_uint(f);
    return (u + 0x7FFFu + ((u >> 16) & 1u)) >> 16;
}
static __device__ __forceinline__ bf16_t f2bf(float f) { return (bf16_t)f2bfbits(f); }
static __device__ __forceinline__ float bf2f(bf16_t h) {
    return __uint_as_float(((unsigned)h) << 16);
}
static __device__ __forceinline__ float bflo(unsigned w) {
    return __uint_as_float(w << 16);
}
static __device__ __forceinline__ float bfhi(unsigned w) {
    return __uint_as_float(w & 0xffff0000u);
}

// ---------------- CSR build (edges sorted by dst), once per call ----------------

__global__ void hist_kernel(const int* __restrict__ ei, int* __restrict__ counts) {
    int e = blockIdx.x * blockDim.x + threadIdx.x;
    if (e < NE) atomicAdd(&counts[ei[NE + e]], 1);
}

__global__ void scan_a_kernel(const int* __restrict__ counts, int* __restrict__ row_start,
                              int* __restrict__ tile_sums) {
    __shared__ int sh[256];
    int t = threadIdx.x;
    int i = blockIdx.x * 256 + t;
    int c = (i < NN) ? counts[i] : 0;
    sh[t] = c;
    __syncthreads();
    for (int ofs = 1; ofs < 256; ofs <<= 1) {
        int v = (t >= ofs) ? sh[t - ofs] : 0;
        __syncthreads();
        sh[t] += v;
        __syncthreads();
    }
    if (i < NN) row_start[i] = sh[t] - c;
    if (t == 255) tile_sums[blockIdx.x] = sh[255];
}

__global__ void scan_b_kernel(int* __restrict__ tile_sums) {
    __shared__ int sh[256];
    int t = threadIdx.x;
    int v = (t < NT) ? tile_sums[t] : 0;
    sh[t] = v;
    __syncthreads();
    for (int ofs = 1; ofs < 256; ofs <<= 1) {
        int u = (t >= ofs) ? sh[t - ofs] : 0;
        __syncthreads();
        sh[t] += u;
        __syncthreads();
    }
    if (t < NT) tile_sums[t] = sh[t] - v;
}

__global__ void scan_c_kernel(int* __restrict__ row_start, const int* __restrict__ tile_sums,
                              int* __restrict__ cursor) {
    int i = blockIdx.x * 256 + threadIdx.x;
    if (i < NN) {
        int v = row_start[i] + tile_sums[blockIdx.x];
        row_start[i] = v;
        cursor[i] = v;
    }
    if (i == 0) row_start[NN] = NE;
}

__global__ void scatter_kernel(const int* __restrict__ ei, int* __restrict__ cursor,
                               int* __restrict__ ssrc) {
    int e = blockIdx.x * blockDim.x + threadIdx.x;
    if (e < NE) {
        int d = ei[NE + e];
        int pos = atomicAdd(&cursor[d], 1);
        ssrc[pos] = ei[e];
    }
}

// ---------------- layer 0: fused gather0 + rank-1 expand + stats ----------------
__global__ __launch_bounds__(256) void layer0_kernel(const float* __restrict__ x,
                                                     const int* __restrict__ row_start,
                                                     const int* __restrict__ ssrc,
                                                     const float* __restrict__ w,
                                                     const float* __restrict__ bias,
                                                     bf16_t* __restrict__ y,
                                                     float* __restrict__ stats) {
    __shared__ float z0p[256];
    __shared__ float z0s[64];
    int t = threadIdx.x, lane = t & 63, wid = t >> 6;
    int r0 = blockIdx.x * 64;
    {
        int node = t >> 2, sub = t & 3;
        int i = r0 + node;
        float acc = 0.f;
        if (i < NN) {
            int pa = row_start[i], pb = row_start[i + 1];
            for (int p = pa + sub; p < pb; p += 4) acc += x[ssrc[p]];
            if (sub == 0) acc += x[i];
        }
        z0p[t] = acc;
    }
    __syncthreads();
    if (t < 64) z0s[t] = z0p[4 * t] + z0p[4 * t + 1] + z0p[4 * t + 2] + z0p[4 * t + 3];
    __syncthreads();
    float wv = w[lane], bv = bias[lane];
    float s = 0.f, s2 = 0.f;
    for (int j = 0; j < 16; ++j) {
        int r = r0 + wid * 16 + j;
        if (r < NN) {
            float v = z0s[wid * 16 + j] * wv + bv;
            y[r * HC + lane] = f2bf(v);
            s += v;
            s2 += v * v;
        }
    }
    __shared__ float ls[256], ls2[256];
    ls[t] = s;
    ls2[t] = s2;
    __syncthreads();
    if (wid == 0) {
        float ts = ls[lane] + ls[64 + lane] + ls[128 + lane] + ls[192 + lane];
        float t2 = ls2[lane] + ls2[64 + lane] + ls2[128 + lane] + ls2[192 + lane];
        atomicAdd(&stats[lane], ts);
        atomicAdd(&stats[64 + lane], t2);
    }
}

// ---------------- K1: BN2(prev)+ReLU fused gather + gdesc(prev) + GEMM1 + stats1 --------
// Phase A (lane=channel): self terms into zs + segmented gdesc.
// Phase B (8-lane groups, uint4=8ch): edge gather, software-pipelined (2 batches in flight).
// Phase C (lane=out channel): 32x64 @ 64x64 GEMM (bf16 transposed weights, stride 33 dw).
__global__ __launch_bounds__(256) void gather_gemm_kernel(
    const bf16_t* __restrict__ u, const float* __restrict__ statsPrev,
    const float* __restrict__ gPrev, const float* __restrict__ bPrev,
    const int* __restrict__ row_start, const int* __restrict__ ssrc,
    const float* __restrict__ w, const float* __restrict__ bias, const int* __restrict__ batch,
    float* __restrict__ gdesc, int layerPrev, bf16_t* __restrict__ out,
    float* __restrict__ statsOut) {
    __shared__ float zs[32 * 64];
    __shared__ unsigned wsmT32[64 * 33];  // [outCol][kPair], stride 33 dw: bank-clean
    __shared__ float a1[64], s1[64];
    __shared__ float red[256];
    int t = threadIdx.x, lane = t & 63, wid = t >> 6;
    int r0 = blockIdx.x * 32;
    if (t < 64) {
        float mu = statsPrev[t] * (1.0f / NN);
        float var = statsPrev[64 + t] * (1.0f / NN) - mu * mu;
        float a = gPrev[t] * rsqrtf(var + BN_EPS);
        a1[t] = a;
        s1[t] = bPrev[t] - mu * a;
    }
    for (int idx = t; idx < 2048; idx += 256) {
        int kk = idx >> 6, c = idx & 63;
        unsigned lo = f2bfbits(w[(2 * kk) * 64 + c]);
        unsigned hi = f2bfbits(w[(2 * kk + 1) * 64 + c]);
        wsmT32[c * 33 + kk] = lo | (hi << 16);
    }
    __syncthreads();
    // ---- Phase A: self terms + segmented gdesc (lane = channel) ----
    {
        float av = a1[lane], sv = s1[lane];
        int col = 1 + layerPrev * HC + lane;
        float gacc = 0.f;
        int cur = -1;
        for (int j = 0; j < 8; ++j) {
            int lr = wid * 8 + j, gr = r0 + lr;
            float hv = 0.f;
            if (gr < NN) {
                hv = fmaxf(bf2f(u[gr * HC + lane]) * av + sv, 0.f);
                int gid = batch[gr];
                if (gid != cur) {
                    if (cur >= 0) atomicAdd(&gdesc[cur * GD_COLS + col], gacc);
                    cur = gid;
                    gacc = 0.f;
                }
                gacc += hv;
            }
            zs[lr * 64 + lane] = hv;
        }
        if (cur >= 0) atomicAdd(&gdesc[cur * GD_COLS + col], gacc);
    }
    // ---- Phase B: pipelined edge gather, 8-lane groups, uint4 (8 bf16 ch) ----
    {
        int li = lane & 7;   // channel block (8 channels)
        int gq = lane >> 3;  // row within wave's 8
        int lr = wid * 8 + gq;
        int n = r0 + lr;
        float a8[8], s8[8];
#pragma unroll
        for (int c = 0; c < 8; ++c) {
            a8[c] = a1[li * 8 + c];
            s8[c] = s1[li * 8 + c];
        }
        float acc[8];
#pragma unroll
        for (int c = 0; c < 8; ++c) acc[c] = 0.f;
        if (n < NN) {
            int pa = row_start[n], pb = row_start[n + 1];
            uint4 rv[8];
            int cntA = 0;
            if (pa < pb) {
                int idx[8];
#pragma unroll
                for (int e = 0; e < 8; ++e) {
                    int pe = pa + e;
                    idx[e] = ssrc[pe < pb ? pe : pb - 1];
                }
#pragma unroll
                for (int e = 0; e < 8; ++e)
                    rv[e] = *(const uint4*)&u[(size_t)idx[e] * HC + li * 8];
                cntA = pb - pa;
                if (cntA > 8) cntA = 8;
            }
            for (int p = pa + 8; cntA > 0; p += 8) {
                uint4 nv[8];
                int cntB = 0;
                if (p < pb) {
                    int idx[8];
#pragma unroll
                    for (int e = 0; e < 8; ++e) {
                        int pe = p + e;
                        idx[e] = ssrc[pe < pb ? pe : pb - 1];
                    }
#pragma unroll
                    for (int e = 0; e < 8; ++e)
                        nv[e] = *(const uint4*)&u[(size_t)idx[e] * HC + li * 8];
                    cntB = pb - p;
                    if (cntB > 8) cntB = 8;
                }
                // accumulate current batch while next batch is in flight
#pragma unroll
                for (int e = 0; e < 8; ++e) {
                    float v0 = fmaxf(bflo(rv[e].x) * a8[0] + s8[0], 0.f);
                    float v1 = fmaxf(bfhi(rv[e].x) * a8[1] + s8[1], 0.f);
                    float v2 = fmaxf(bflo(rv[e].y) * a8[2] + s8[2], 0.f);
                    float v3 = fmaxf(bfhi(rv[e].y) * a8[3] + s8[3], 0.f);
                    float v4 = fmaxf(bflo(rv[e].z) * a8[4] + s8[4], 0.f);
                    float v5 = fmaxf(bfhi(rv[e].z) * a8[5] + s8[5], 0.f);
                    float v6 = fmaxf(bflo(rv[e].w) * a8[6] + s8[6], 0.f);
                    float v7 = fmaxf(bfhi(rv[e].w) * a8[7] + s8[7], 0.f);
                    if (e < cntA) {
                        acc[0] += v0;
                        acc[1] += v1;
                        acc[2] += v2;
                        acc[3] += v3;
                        acc[4] += v4;
                        acc[5] += v5;
                        acc[6] += v6;
                        acc[7] += v7;
                    }
                }
#pragma unroll
                for (int e = 0; e < 8; ++e) rv[e] = nv[e];
                cntA = cntB;
            }
        }
        float4 z0v = *(float4*)&zs[lr * 64 + li * 8];
        z0v.x += acc[0];
        z0v.y += acc[1];
        z0v.z += acc[2];
        z0v.w += acc[3];
        *(float4*)&zs[lr * 64 + li * 8] = z0v;
        float4 z1v = *(float4*)&zs[lr * 64 + li * 8 + 4];
        z1v.x += acc[4];
        z1v.y += acc[5];
        z1v.z += acc[6];
        z1v.w += acc[7];
        *(float4*)&zs[lr * 64 + li * 8 + 4] = z1v;
    }
    // ---- Phase C: GEMM1 + stats1 (lane = out channel) — wave-local rows ----
    float bv = bias[lane];
    float ssum = 0.f, ssq = 0.f;
    for (int j = 0; j < 8; ++j) {
        int r = wid * 8 + j;
        float acc = 0.f;
#pragma unroll
        for (int k = 0; k < 64; k += 4) {
            float4 zv = *(const float4*)&zs[r * 64 + k];  // broadcast
            unsigned w0 = wsmT32[lane * 33 + (k >> 1)];
            unsigned w1 = wsmT32[lane * 33 + (k >> 1) + 1];
            acc += zv.x * bflo(w0);
            acc += zv.y * bfhi(w0);
            acc += zv.z * bflo(w1);
            acc += zv.w * bfhi(w1);
        }
        acc += bv;
        int gr = r0 + r;
        if (gr < NN) {
            out[gr * HC + lane] = f2bf(acc);
            ssum += acc;
            ssq += acc * acc;
        }
    }
    red[t] = ssum;
    __syncthreads();
    if (wid == 0) {
        float ts = red[lane] + red[64 + lane] + red[128 + lane] + red[192 + lane];
        atomicAdd(&statsOut[lane], ts);
    }
    __syncthreads();
    red[t] = ssq;
    __syncthreads();
    if (wid == 0) {
        float t2 = red[lane] + red[64 + lane] + red[128 + lane] + red[192 + lane];
        atomicAdd(&statsOut[64 + lane], t2);
    }
}

// ---------------- K2: BN1+ReLU fused GEMM2 + stats2 (32 rows/block, bf16 io) ----------------
__global__ __launch_bounds__(256) void gemm64_norm_kernel(
    const bf16_t* __restrict__ in, const float* __restrict__ w, const float* __restrict__ bias,
    const float* __restrict__ statsIn, const float* __restrict__ gIn,
    const float* __restrict__ bIn, bf16_t* __restrict__ out, float* __restrict__ statsOut) {
    __shared__ float zs[32 * 64];
    __shared__ unsigned wsmT32[64 * 33];
    __shared__ float a1[64], s1[64];
    __shared__ float red[256];
    int t = threadIdx.x;
    if (t < 64) {
        float mu = statsIn[t] * (1.0f / NN);
        float var = statsIn[64 + t] * (1.0f / NN) - mu * mu;
        float a = gIn[t] * rsqrtf(var + BN_EPS);
        a1[t] = a;
        s1[t] = bIn[t] - mu * a;
    }
    for (int idx = t; idx < 2048; idx += 256) {
        int kk = idx >> 6, c = idx & 63;
        unsigned lo = f2bfbits(w[(2 * kk) * 64 + c]);
        unsigned hi = f2bfbits(w[(2 * kk + 1) * 64 + c]);
        wsmT32[c * 33 + kk] = lo | (hi << 16);
    }
    __syncthreads();
    int r0 = blockIdx.x * 32;
    for (int idx = t; idx < 512; idx += 256) {
        int off = idx * 4;
        int r = r0 + (off >> 6);
        int k = off & 63;
        float4 v = make_float4(0.f, 0.f, 0.f, 0.f);
        if (r < NN) {
            ushort4 uv = *(const ushort4*)&in[r * HC + k];
            v.x = bf2f(uv.x);
            v.y = bf2f(uv.y);
            v.z = bf2f(uv.z);
            v.w = bf2f(uv.w);
        }
        v.x = fmaxf(v.x * a1[k] + s1[k], 0.f);
        v.y = fmaxf(v.y * a1[k + 1] + s1[k + 1], 0.f);
        v.z = fmaxf(v.z * a1[k + 2] + s1[k + 2], 0.f);
        v.w = fmaxf(v.w * a1[k + 3] + s1[k + 3], 0.f);
        *(float4*)&zs[off] = v;
    }
    __syncthreads();
    int lane = t & 63, wid = t >> 6;
    float bv = bias[lane];
    float ssum = 0.f, ssq = 0.f;
    for (int j = 0; j < 8; ++j) {
        int r = wid * 8 + j;
        float acc = 0.f;
#pragma unroll
        for (int k = 0; k < 64; k += 4) {
            float4 zv = *(const float4*)&zs[r * 64 + k];
            unsigned w0 = wsmT32[lane * 33 + (k >> 1)];
            unsigned w1 = wsmT32[lane * 33 + (k >> 1) + 1];
            acc += zv.x * bflo(w0);
            acc += zv.y * bfhi(w0);
            acc += zv.z * bflo(w1);
            acc += zv.w * bfhi(w1);
        }
        acc += bv;
        int gr = r0 + r;
        if (gr < NN) {
            out[gr * HC + lane] = f2bf(acc);
            ssum += acc;
            ssq += acc * acc;
        }
    }
    red[t] = ssum;
    __syncthreads();
    if (wid == 0) {
        float ts = red[lane] + red[64 + lane] + red[128 + lane] + red[192 + lane];
        atomicAdd(&statsOut[lane], ts);
    }
    __syncthreads();
    red[t] = ssq;
    __syncthreads();
    if (wid == 0) {
        float t2 = red[lane] + red[64 + lane] + red[128 + lane] + red[192 + lane];
        atomicAdd(&statsOut[64 + lane], t2);
    }
}

// ---------------- last-layer gdesc (BN2+ReLU, segmented sum, no h write) ----------------
#define CHK 16
__global__ void gdesc_last_kernel(const bf16_t* __restrict__ u, const float* __restrict__ stats,
                                  const float* __restrict__ g, const float* __restrict__ b,
                                  const int* __restrict__ batch, float* __restrict__ gdesc,
                                  int layer) {
    int lane = threadIdx.x & 63;
    int wid = threadIdx.x >> 6;
    int i0 = (blockIdx.x * 4 + wid) * CHK;
    if (i0 >= NN) return;
    float mu = stats[lane] * (1.0f / NN);
    float var = stats[64 + lane] * (1.0f / NN) - mu * mu;
    float a = g[lane] * rsqrtf(var + BN_EPS);
    float s = b[lane] - mu * a;
    int col = 1 + layer * HC + lane;
    float acc = 0.f;
    int cur = -1;
    int iend = i0 + CHK;
    if (iend > NN) iend = NN;
    for (int i = i0; i < iend; ++i) {
        int gid = batch[i];
        if (gid != cur) {
            if (cur >= 0) atomicAdd(&gdesc[cur * GD_COLS + col], acc);
            cur = gid;
            acc = 0.f;
        }
        acc += fmaxf(bf2f(u[i * HC + lane]) * a + s, 0.f);
    }
    if (cur >= 0) atomicAdd(&gdesc[cur * GD_COLS + col], acc);
}

__global__ void first_desc_kernel(const float* __restrict__ x, const int* __restrict__ batch,
                                  float* __restrict__ gdesc) {
    int i = blockIdx.x * blockDim.x + threadIdx.x;
    if (i < NN) atomicAdd(&gdesc[batch[i] * GD_COLS], x[i]);
}

__global__ void final_gemm_kernel(const float* __restrict__ gdesc, const float* __restrict__ lw,
                                  const float* __restrict__ lb, float* __restrict__ out) {
    int g = blockIdx.x;
    int lane = threadIdx.x;  // 64
    float a0 = 0.f, a1 = 0.f;
    for (int j = lane; j < GD_COLS; j += 64) {
        float v = gdesc[g * GD_COLS + j];
        a0 += v * lw[j * 2 + 0];
        a1 += v * lw[j * 2 + 1];
    }
    for (int off = 32; off > 0; off >>= 1) {
        a0 += __shfl_down(a0, off);
        a1 += __shfl_down(a1, off);
    }
    if (lane == 0) {
        out[g * 2 + 0] = a0 + lb[0];
        out[g * 2 + 1] = a1 + lb[1];
    }
}

extern "C" void kernel_launch(void* const* d_in, const int* in_sizes, int n_in, void* d_out,
                              int out_size, void* d_ws, size_t ws_size, hipStream_t stream) {
    const float* x = (const float*)d_in[0];
    const int* ei = (const int*)d_in[1];
    const int* batch = (const int*)d_in[2];
    const float* w1_0 = (const float*)d_in[3];
    const float* w1_rest = (const float*)d_in[4];
    const float* b1 = (const float*)d_in[5];
    const float* gm = (const float*)d_in[6];
    const float* bm = (const float*)d_in[7];
    const float* w2 = (const float*)d_in[8];
    const float* b2 = (const float*)d_in[9];
    const float* go = (const float*)d_in[10];
    const float* bo = (const float*)d_in[11];
    const float* lw = (const float*)d_in[12];
    const float* lb = (const float*)d_in[13];
    float* out = (float*)d_out;

    float* stats = (float*)d_ws;                     // NL*256
    float* gdesc = stats + NL * 256;                 // NG*321
    bf16_t* ybuf = (bf16_t*)(gdesc + (size_t)NG * GD_COLS + 64);  // NN*64 bf16
    bf16_t* ubuf = ybuf + (size_t)NN * HC;           // NN*64 bf16
    int* row_start = (int*)(ubuf + (size_t)NN * HC); // NN+1
    int* cursor = row_start + NN + 1;                // NN (also counts)
    int* tile_sums = cursor + NN;                    // 256
    int* ssrc = tile_sums + 256;                     // NE

    hipMemsetAsync(stats, 0, (NL * 256 + NG * GD_COLS) * sizeof(float), stream);
    hipMemsetAsync(cursor, 0, NN * sizeof(int), stream);  // counts

    // ---- CSR build (once; edges constant across layers) ----
    hist_kernel<<<(NE + 255) / 256, 256, 0, stream>>>(ei, cursor);
    scan_a_kernel<<<NT, 256, 0, stream>>>(cursor, row_start, tile_sums);
    scan_b_kernel<<<1, 256, 0, stream>>>(tile_sums);
    scan_c_kernel<<<NT, 256, 0, stream>>>(row_start, tile_sums, cursor);
    scatter_kernel<<<(NE + 255) / 256, 256, 0, stream>>>(ei, cursor, ssrc);

    // ---- layer 0 ----
    layer0_kernel<<<(NN + 63) / 64, 256, 0, stream>>>(x, row_start, ssrc, w1_0, b1, ybuf, stats);
    gemm64_norm_kernel<<<(NN + 31) / 32, 256, 0, stream>>>(ybuf, w2, b2, stats, gm, bm, ubuf,
                                                           stats + 128);

    // ---- layers 1..4 (K1 applies BN2 of prev layer + gdesc of prev layer) ----
    for (int l = 1; l < NL; ++l) {
        float* st1 = stats + l * 256;
        float* st2 = st1 + 128;
        float* stPrev = stats + (l - 1) * 256 + 128;
        gather_gemm_kernel<<<(NN + 31) / 32, 256, 0, stream>>>(
            ubuf, stPrev, go + (l - 1) * HC, bo + (l - 1) * HC, row_start, ssrc,
            w1_rest + (size_t)(l - 1) * HC * HC, b1 + l * HC, batch, gdesc, l - 1, ybuf, st1);
        gemm64_norm_kernel<<<(NN + 31) / 32, 256, 0, stream>>>(
            ybuf, w2 + (size_t)l * HC * HC, b2 + l * HC, st1, gm + l * HC, bm + l * HC, ubuf, st2);
    }

    gdesc_last_kernel<<<(NN + 4 * CHK - 1) / (4 * CHK), 256, 0, stream>>>(
        ubuf, stats + 4 * 256 + 128, go + 4 * HC, bo + 4 * HC, batch, gdesc, 4);
    first_desc_kernel<<<(NN + 255) / 256, 256, 0, stream>>>(x, batch, gdesc);
    final_gemm_kernel<<<NG, 64, 0, stream>>>(gdesc, lw, lb, out);
}